// Round 12
// baseline (1078.151 us; speedup 1.0000x reference)
//
#include <hip/hip_runtime.h>
#include <math.h>

#define EPS 1e-8f

typedef _Float16 h2_t __attribute__((ext_vector_type(2)));
typedef _Float16 half8 __attribute__((ext_vector_type(8)));
typedef float f32x4 __attribute__((ext_vector_type(4)));

__device__ __forceinline__ float fsig(float x)  { return 1.0f / (1.0f + __expf(-x)); }
__device__ __forceinline__ float ftanh(float x) { return 1.0f - 2.0f / (1.0f + __expf(2.0f * x)); }

// Wave-level 16B/lane global->LDS DMA (no VGPR round trip). LDS dest is
// wave-uniform base + lane*16; global src is per-lane.
__device__ __forceinline__ void gload16(const _Float16* g, _Float16* lds) {
    __builtin_amdgcn_global_load_lds(
        (const __attribute__((address_space(1))) void*)g,
        (__attribute__((address_space(3))) void*)lds, 16, 0, 0);
}

// Quad butterfly sum via DPP (VALU pipe) -- all 4 lanes get the full sum.
__device__ __forceinline__ float qsum4(float x) {
    int y1 = __builtin_amdgcn_update_dpp(
        0, __builtin_bit_cast(int, x), 0xB1, 0xF, 0xF, true);   // quad_perm [1,0,3,2]
    float s1 = x + __builtin_bit_cast(float, y1);
    int y2 = __builtin_amdgcn_update_dpp(
        0, __builtin_bit_cast(int, s1), 0x4E, 0xF, 0xF, true);  // quad_perm [2,3,0,1]
    return s1 + __builtin_bit_cast(float, y2);
}

// ---------------------------------------------------------------------------
// Weight prep: W_ih stacks -> fp16 [768,320pad]/[768,512]; W_hh -> fp16
// [2][384][128]; biases fp32.
// ---------------------------------------------------------------------------
__global__ __launch_bounds__(256) void prep_w_k(
    const float* __restrict__ rwf, const float* __restrict__ rwb,
    const float* __restrict__ awf, const float* __restrict__ awb,
    const float* __restrict__ rbf, const float* __restrict__ rbb,
    const float* __restrict__ abf, const float* __restrict__ abb,
    const float* __restrict__ rhf, const float* __restrict__ rhb,
    const float* __restrict__ ahf, const float* __restrict__ ahb,
    _Float16* __restrict__ wrh, _Float16* __restrict__ wah,
    _Float16* __restrict__ wr16, _Float16* __restrict__ wa16,
    float* __restrict__ br, float* __restrict__ ba)
{
    int idx = blockIdx.x * 256 + threadIdx.x;
    if (idx < 768 * 320) {
        int g = idx / 320, k = idx % 320;
        float v = 0.f;
        if (k < 300) v = (g < 384) ? rwf[g * 300 + k] : rwb[(g - 384) * 300 + k];
        wrh[idx] = (_Float16)v;
    }
    if (idx < 768 * 512) {
        int g = idx / 512, k = idx % 512;
        wah[idx] = (_Float16)((g < 384) ? awf[g * 512 + k] : awb[(g - 384) * 512 + k]);
    }
    if (idx < 2 * 384 * 128) {
        int d = idx / 49152, r = idx % 49152;
        wr16[idx] = (_Float16)(d ? rhb[r] : rhf[r]);
        wa16[idx] = (_Float16)(d ? ahb[r] : ahf[r]);
    }
    if (idx < 768) {
        br[idx] = (idx < 384) ? rbf[idx] : rbb[idx - 384];
        ba[idx] = (idx < 384) ? abf[idx] : abb[idx - 384];
    }
}

// ---------------------------------------------------------------------------
// Input conversion fp32 -> fp16 (K padded 300->320 with zeros).
// ---------------------------------------------------------------------------
__global__ __launch_bounds__(256) void conv_k(
    const float* __restrict__ ctx, const float* __restrict__ opt,
    _Float16* __restrict__ ctxh, _Float16* __restrict__ opth)
{
    int idx = blockIdx.x * 256 + threadIdx.x;
    if (idx < 32768 * 320) {
        int r = idx / 320, k = idx % 320;
        ctxh[idx] = (k < 300) ? (_Float16)ctx[r * 300 + k] : (_Float16)0.f;
    }
    if (idx < 32000 * 320) {
        int r = idx / 320, k = idx % 320;
        opth[idx] = (k < 300) ? (_Float16)opt[r * 300 + k] : (_Float16)0.f;
    }
}

// ---------------------------------------------------------------------------
// fp16 MFMA GEMM, 64x64 tile, BK=64, 256 threads = 4 waves (2x2 of 32x32).
// C[z] = A[z] * B[z/bdiv]^T + bias, fp32 accumulate, fp16 out.
// TRBS:   B given as [K][N] row-major -> transpose-stage into LDS.
// SPLITA: A = [A|A2] along K (each lda wide, fp16).
// DIRECT: stage via global_load_lds (wave DMA, 16B/lane) -- requires
//         M % 64 == 0 (no predication) and !TRBS.
// K must be a multiple of 64 (320/256/512 all are).
// ---------------------------------------------------------------------------
template <bool TRBS, bool SPLITA, bool HASBIAS, bool DIRECT>
__global__ __launch_bounds__(256, 4) void hgemm_k(
    const _Float16* __restrict__ A, const _Float16* __restrict__ A2,
    const _Float16* __restrict__ B, const float* __restrict__ bias,
    _Float16* __restrict__ C, int M, int N, int K,
    int lda, int ldb, int ldc, long sA, long sB, int bdiv, long sC)
{
    static_assert(!(DIRECT && TRBS), "DIRECT requires NT B layout");
    const int jn = blockIdx.x * 64;
    const int im = blockIdx.y * 64;
    const int z  = blockIdx.z;
    const _Float16* Bb = B + (size_t)(z / bdiv) * sB;
    _Float16* Cb = C + (size_t)z * sC;

    __shared__ __align__(16) _Float16 As[64 * 64];
    __shared__ __align__(16) _Float16 Bs[64 * 64];

    const int tid  = threadIdx.x;
    const int arow = tid >> 2;          // 0..63
    const int akof = (tid & 3) * 8;     // 0,8,16,24
    const int lane = tid & 63;
    const int wv   = tid >> 6;          // 0..3
    const int wm   = (wv & 1) * 32;
    const int wn   = (wv >> 1) * 32;
    const int fm   = lane & 15;
    const int quad = lane >> 4;

    f32x4 acc[2][2];
#pragma unroll
    for (int a = 0; a < 2; a++)
#pragma unroll
        for (int b = 0; b < 2; b++) acc[a][b] = (f32x4)0.f;

    for (int k0 = 0; k0 < K; k0 += 64) {
        if constexpr (DIRECT) {
            // wave-level DMA: wave wv stages 8-row chunks rb=8*wv, 8*(wv+4)
            // of both As and Bs. lane j covers row rb+(j>>3), k (j&7)*8.
            const int r8 = lane >> 3;
            const int kg = k0 + (lane & 7) * 8;
#pragma unroll
            for (int hh = 0; hh < 2; hh++) {
                const int rb = 8 * (wv + 4 * hh);
                const _Float16* gA;
                if constexpr (SPLITA) {
                    const _Float16* Ah  = A  + (size_t)z * sA;
                    const _Float16* A2h = A2 + (size_t)z * sA;
                    gA = (kg < 256)
                        ? (Ah  + (size_t)(im + rb + r8) * lda + kg)
                        : (A2h + (size_t)(im + rb + r8) * lda + (kg - 256));
                } else {
                    gA = A + (size_t)z * sA + (size_t)(im + rb + r8) * lda + kg;
                }
                gload16(gA, &As[rb * 64]);
                gload16(Bb + (size_t)(jn + rb + r8) * ldb + kg, &Bs[rb * 64]);
            }
        } else {
            // ---- A tile: 64 rows x 64 k (2 half8 per thread)
            {
                const int row = im + arow;
#pragma unroll
                for (int hh = 0; hh < 2; hh++) {
                    half8 av = (half8)(_Float16)0.f;
                    const int kg = k0 + akof + 32 * hh;
                    if (row < M) {
                        if constexpr (SPLITA) {
                            const _Float16* Ah  = A + (size_t)z * sA;
                            const _Float16* A2h = A2 + (size_t)z * sA;
                            const _Float16* ap = (kg < 256)
                                ? (Ah + (size_t)row * lda + kg)
                                : (A2h + (size_t)row * lda + (kg - 256));
                            av = *(const half8*)ap;
                        } else {
                            av = *(const half8*)(A + (size_t)z * sA + (size_t)row * lda + kg);
                        }
                    }
                    *(half8*)&As[arow * 64 + akof + 32 * hh] = av;
                }
            }
            // ---- B tile
            if constexpr (!TRBS) {          // B [N][K] rm (NT)
#pragma unroll
                for (int hh = 0; hh < 2; hh++) {
                    half8 bv = *(const half8*)(Bb + (size_t)(jn + arow) * ldb
                                               + k0 + akof + 32 * hh);
                    *(half8*)&Bs[arow * 64 + akof + 32 * hh] = bv;
                }
            } else {                        // B [K][N] rm -> LDS [n][k]
                const int kk = tid >> 3, noff = (tid & 7) * 8;
                half8 bv0 = *(const half8*)(Bb + (size_t)(k0 + kk) * ldb + jn + noff);
                half8 bv1 = *(const half8*)(Bb + (size_t)(k0 + kk + 32) * ldb + jn + noff);
#pragma unroll
                for (int e = 0; e < 8; e++) {
                    Bs[(noff + e) * 64 + kk]      = bv0[e];
                    Bs[(noff + e) * 64 + kk + 32] = bv1[e];
                }
            }
        }
        __syncthreads();

        const _Float16* Asp = As + (wm + fm) * 64 + quad * 8;
        const _Float16* Bsp = Bs + (wn + fm) * 64 + quad * 8;
#pragma unroll
        for (int kh = 0; kh < 64; kh += 32) {
            half8 a0 = *(const half8*)(Asp + kh);
            half8 a1 = *(const half8*)(Asp + 16 * 64 + kh);
            half8 b0 = *(const half8*)(Bsp + kh);
            half8 b1 = *(const half8*)(Bsp + 16 * 64 + kh);
            acc[0][0] = __builtin_amdgcn_mfma_f32_16x16x32_f16(a0, b0, acc[0][0], 0, 0, 0);
            acc[0][1] = __builtin_amdgcn_mfma_f32_16x16x32_f16(a0, b1, acc[0][1], 0, 0, 0);
            acc[1][0] = __builtin_amdgcn_mfma_f32_16x16x32_f16(a1, b0, acc[1][0], 0, 0, 0);
            acc[1][1] = __builtin_amdgcn_mfma_f32_16x16x32_f16(a1, b1, acc[1][1], 0, 0, 0);
        }
        __syncthreads();
    }

#pragma unroll
    for (int tm = 0; tm < 2; tm++) {
#pragma unroll
        for (int tn = 0; tn < 2; tn++) {
            const int col  = jn + wn + tn * 16 + fm;
            const int row0 = im + wm + tm * 16 + quad * 4;
            const float bv = HASBIAS ? bias[col] : 0.f;
#pragma unroll
            for (int r = 0; r < 4; r++) {
                const int row = row0 + r;
                if (DIRECT || row < M)
                    Cb[(size_t)row * ldc + col] = (_Float16)(acc[tm][tn][r] + bv);
            }
        }
    }
}

// ---------------------------------------------------------------------------
// GRU recurrence v18 = v15 (R9, verified: ctx 307us, absmax 4.88e-4) with
// ONE scheduling tweak: the three gxs reads hoisted to the top of the step
// body so their ~120cy LDS latency overlaps the 16-deep fdot2 chain. Reads
// of two disjoint read-only-in-loop LDS arrays reordered -- no write
// interactions, bit-identical math. R11's b128 h-read formulation is
// REVERTED (run-variant absmax 7.8e-3..468 => scheduling hazard around the
// h1 double-buffer that the scalar h2 form does not have).
// ---------------------------------------------------------------------------
template <int TCMAX>
__global__ __launch_bounds__(512, 2) void gru_rec_k(
    const _Float16* __restrict__ gx,
    const _Float16* __restrict__ whh16,   // [2][384][128] fp16, dir-major
    const float* __restrict__ bhh_f, const float* __restrict__ bhh_b,
    _Float16* __restrict__ outs_h, float* __restrict__ hfin, int L)
{
    const int dir = blockIdx.x & 1;
    const int s   = blockIdx.x >> 1;
    const int t   = threadIdx.x;
    const int w   = t >> 6;
    const int l   = t & 63;
    const int i   = w * 16 + (l >> 2);  // output index (one per quad)
    const int kq  = l & 3;              // k-quarter within quad
    const _Float16* Wd = whh16 + (size_t)dir * 49152;
    const float* bh = dir ? bhh_b : bhh_f;

    h2_t w2[3][16];
#pragma unroll
    for (int j = 0; j < 3; j++) {
        const _Float16* Wr = Wd + (size_t)(i + 128 * j) * 128 + 32 * kq;
#pragma unroll
        for (int q = 0; q < 16; q++)
            w2[j][q] = *(const h2_t*)(Wr + 2 * q);
    }
    const float b0 = bh[i], b1 = bh[i + 128], b2 = bh[i + 256];

    __shared__ __align__(16) _Float16 h1[2][128];
    __shared__ __align__(16) _Float16 gxs[TCMAX][384];
    __shared__ __align__(16) _Float16 outb[TCMAX][128];
    if (t < 128) h1[0][t] = (_Float16)0.f;
    float hprev = 0.f;

    constexpr int NST = (TCMAX * 48 + 511) / 512;   // staging chunks/thread
    constexpr int NFL = (TCMAX * 16 + 511) / 512;   // flush chunks/thread

    for (int t0 = 0; t0 < L; t0 += TCMAX) {
        const int Tc = (L - t0 < TCMAX) ? (L - t0) : TCMAX;
        // stage gx tile (Tc*48 half8 chunks over 512 threads)
#pragma unroll
        for (int r = 0; r < NST; r++) {
            const int q = t + 512 * r;
            if (q < Tc * 48) {
                const int j = q / 48, off = (q % 48) * 8;
                const int tt = dir ? (L - 1 - (t0 + j)) : (t0 + j);
                *(half8*)&gxs[j][off] =
                    *(const half8*)(gx + ((size_t)s * L + tt) * 768 + dir * 384 + off);
            }
        }
        __syncthreads();   // drains staging; orders h1 init / prev flush

        for (int j = 0; j < Tc; j++) {
            const int cb = (t0 + j) & 1;
            // gxs reads first: their latency overlaps the fdot2 chain.
            const float xc0 = (float)gxs[j][i];
            const float xc1 = (float)gxs[j][i + 128];
            const float xc2 = (float)gxs[j][i + 256];
            const h2_t* hp = (const h2_t*)&h1[cb][32 * kq];
            float a0 = 0.f, a1 = 0.f, a2 = 0.f;
#pragma unroll
            for (int q = 0; q < 16; q++) {
                h2_t hq = hp[q];
                a0 = __builtin_amdgcn_fdot2(w2[0][q], hq, a0, false);
                a1 = __builtin_amdgcn_fdot2(w2[1][q], hq, a1, false);
                a2 = __builtin_amdgcn_fdot2(w2[2][q], hq, a2, false);
            }
            a0 = qsum4(a0);
            a1 = qsum4(a1);
            a2 = qsum4(a2);
            const float r  = fsig(xc0 + a0 + b0);
            const float zz = fsig(xc1 + a1 + b1);
            const float n  = ftanh(xc2 + r * (a2 + b2));
            const float hnew = (1.0f - zz) * n + zz * hprev;
            hprev = hnew;
            if (kq == 0) {
                h1[cb ^ 1][i] = (_Float16)hnew;
                outb[j][i]    = (_Float16)hnew;
            }
            __syncthreads();
        }

        // bulk flush outs tile (Tc*16 half8 chunks)
        if (outs_h) {
#pragma unroll
            for (int r = 0; r < NFL; r++) {
                const int q = t + 512 * r;
                if (q < Tc * 16) {
                    const int j = q / 16, off = (q % 16) * 8;
                    const int tt = dir ? (L - 1 - (t0 + j)) : (t0 + j);
                    *(half8*)(outs_h + ((size_t)s * L + tt) * 256 + dir * 128 + off) =
                        *(const half8*)&outb[j][off];
                }
            }
        }
    }
    if (hfin && kq == 0) hfin[(size_t)s * 256 + dir * 128 + i] = hprev;
}

// ---------------------------------------------------------------------------
// Row inverse norms over fp16 rows of 256.
// ---------------------------------------------------------------------------
__global__ __launch_bounds__(256) void rowinv_k(const _Float16* __restrict__ x,
                                                float* __restrict__ rinv)
{
    const int row = blockIdx.x;
    float v = (float)x[(size_t)row * 256 + threadIdx.x];
    float ss = v * v;
#pragma unroll
    for (int o = 32; o > 0; o >>= 1) ss += __shfl_down(ss, o);
    __shared__ float ps[4];
    if ((threadIdx.x & 63) == 0) ps[threadIdx.x >> 6] = ss;
    __syncthreads();
    if (threadIdx.x == 0)
        rinv[row] = 1.0f / fmaxf(sqrtf(ps[0] + ps[1] + ps[2] + ps[3]), EPS);
}

// ---------------------------------------------------------------------------
// Fused cosine-scale + softmax (fp16 in/out, 512 positions).
// ---------------------------------------------------------------------------
__global__ __launch_bounds__(256) void att_softmax_k(
    _Float16* __restrict__ att, const float* __restrict__ rinv_opt_l,
    const float* __restrict__ rinv_ctx, int sbase)
{
    const int row = blockIdx.x;
    const int b = (sbase + row / 50) / 10;
    _Float16* p = att + (size_t)row * 512;
    const float* rc = rinv_ctx + b * 512;
    const float sA = rinv_opt_l[row];
    const int t = threadIdx.x;

    float v0 = (float)p[t]       * (sA * rc[t]);
    float v1 = (float)p[t + 256] * (sA * rc[t + 256]);

    __shared__ float red[4];
    float m = fmaxf(v0, v1);
#pragma unroll
    for (int o = 32; o > 0; o >>= 1) m = fmaxf(m, __shfl_down(m, o));
    if ((t & 63) == 0) red[t >> 6] = m;
    __syncthreads();
    m = fmaxf(fmaxf(red[0], red[1]), fmaxf(red[2], red[3]));
    float e0 = __expf(v0 - m), e1 = __expf(v1 - m);
    float ssum = e0 + e1;
#pragma unroll
    for (int o = 32; o > 0; o >>= 1) ssum += __shfl_down(ssum, o);
    __syncthreads();
    if ((t & 63) == 0) red[t >> 6] = ssum;
    __syncthreads();
    float inv = 1.0f / (red[0] + red[1] + red[2] + red[3]);
    p[t]       = (_Float16)(e0 * inv);
    p[t + 256] = (_Float16)(e1 * inv);
}

// ---------------------------------------------------------------------------
// logits[s] = cosine(ctx_h[s/10], ao_h[s])
// ---------------------------------------------------------------------------
__global__ __launch_bounds__(256) void logits_k(const float* __restrict__ ch,
                                                const float* __restrict__ ah,
                                                float* __restrict__ logits)
{
    const int s = blockIdx.x;
    const int b = s / 10;
    const int t = threadIdx.x;
    float a = ch[b * 256 + t];
    float c = ah[(size_t)s * 256 + t];
    float num = a * c, na = a * a, nc = c * c;
#pragma unroll
    for (int o = 32; o > 0; o >>= 1) {
        num += __shfl_down(num, o);
        na  += __shfl_down(na,  o);
        nc  += __shfl_down(nc,  o);
    }
    __shared__ float pn[4], pa[4], pc[4];
    if ((t & 63) == 0) { pn[t >> 6] = num; pa[t >> 6] = na; pc[t >> 6] = nc; }
    __syncthreads();
    if (t == 0) {
        float sn = pn[0] + pn[1] + pn[2] + pn[3];
        float sa = pa[0] + pa[1] + pa[2] + pa[3];
        float sc = pc[0] + pc[1] + pc[2] + pc[3];
        logits[s] = sn / (fmaxf(sqrtf(sa), EPS) * fmaxf(sqrtf(sc), EPS));
    }
}

// ---------------------------------------------------------------------------
__global__ __launch_bounds__(64) void soft10_k(const float* __restrict__ logits,
                                               float* __restrict__ out)
{
    const int b = blockIdx.x;
    const int t = threadIdx.x;
    __shared__ float v[10];
    if (t < 10) v[t] = logits[b * 10 + t];
    __syncthreads();
    if (t < 10) {
        float m = v[0];
#pragma unroll
        for (int i = 1; i < 10; i++) m = fmaxf(m, v[i]);
        float ssum = 0.f;
#pragma unroll
        for (int i = 0; i < 10; i++) ssum += __expf(v[i] - m);
        out[b * 10 + t] = __expf(v[t] - m) / ssum;
    }
}

// ---------------------------------------------------------------------------
extern "C" void kernel_launch(void* const* d_in, const int* in_sizes, int n_in,
                              void* d_out, int out_size, void* d_ws, size_t ws_size,
                              hipStream_t stream)
{
    const float* context = (const float*)d_in[0];
    const float* options = (const float*)d_in[2];
    const float* rw_ih_f = (const float*)d_in[4];
    const float* rw_hh_f = (const float*)d_in[5];
    const float* rb_ih_f = (const float*)d_in[6];
    const float* rb_hh_f = (const float*)d_in[7];
    const float* rw_ih_b = (const float*)d_in[8];
    const float* rw_hh_b = (const float*)d_in[9];
    const float* rb_ih_b = (const float*)d_in[10];
    const float* rb_hh_b = (const float*)d_in[11];
    const float* aw_ih_f = (const float*)d_in[12];
    const float* aw_hh_f = (const float*)d_in[13];
    const float* ab_ih_f = (const float*)d_in[14];
    const float* ab_hh_f = (const float*)d_in[15];
    const float* aw_ih_b = (const float*)d_in[16];
    const float* aw_hh_b = (const float*)d_in[17];
    const float* ab_ih_b = (const float*)d_in[18];
    const float* ab_hh_b = (const float*)d_in[19];

    // --- chunk config. persist(fl) = 15,222,144 (~60.9 MB).
    //     ATT lives INSIDE the POOL (disjoint lifetimes). pool =
    //     max(bc*196608, sc*32000); extras = 2*sc*6400 (P2H,P3H).
    const size_t persist = 15222144;
    static const int cands[6][2] = {{1,2},{1,4},{2,4},{2,8},{4,16},{8,16}};
    int CC = 8, OC = 16;
    for (int idx = 0; idx < 6; idx++) {
        size_t bc_ = 64 / cands[idx][0], sc_ = 640 / cands[idx][1];
        size_t p = bc_ * 196608;
        if (sc_ * 32000 > p) p = sc_ * 32000;
        if ((persist + p + 2 * sc_ * 6400) * 4 <= ws_size) {
            CC = cands[idx][0]; OC = cands[idx][1]; break;
        }
    }
    const int bc = 64 / CC;
    const int sc = 640 / OC;
    size_t poolsz = (size_t)bc * 196608;
    if ((size_t)sc * 32000 > poolsz) poolsz = (size_t)sc * 32000;

    float* ws = (float*)d_ws;
    size_t off = 0;
    _Float16* wrh   = (_Float16*)(ws + off); off += 122880;   // [768][320] h
    float*    br    = ws + off;              off += 768;
    _Float16* wah   = (_Float16*)(ws + off); off += 196608;   // [768][512] h
    float*    ba    = ws + off;              off += 768;
    _Float16* wr16  = (_Float16*)(ws + off); off += 49152;    // [2][384][128] h
    _Float16* wa16  = (_Float16*)(ws + off); off += 49152;    // [2][384][128] h
    _Float16* couts = (_Float16*)(ws + off); off += 4194304;  // [64*512][256] h
    float*    ctxhf = ws + off;              off += 16384;    // ctx h_fin
    float*    aohf  = ws + off;              off += 163840;   // ao h_fin
    float*    logits= ws + off;              off += 640;
    float*    rinvc = ws + off;              off += 32768;
    float*    rinvo = ws + off;              off += 32000;
    _Float16* ctxh  = (_Float16*)(ws + off); off += 5242880;  // [32768][320] h
    _Float16* opth  = (_Float16*)(ws + off); off += 5120000;  // [32000][320] h
    _Float16* POOL  = (_Float16*)(ws + off); off += poolsz;   // gx pool (+ATT)
    _Float16* P2H   = (_Float16*)(ws + off); off += (size_t)sc * 6400;
    _Float16* P3H   = (_Float16*)(ws + off); off += (size_t)sc * 6400;
    _Float16* ATT   = POOL + (size_t)sc * 38400;  // halfs offset (= sc*19200 fl)

    // 1. weights -> fp16; inputs -> fp16 (padded K=320)
    prep_w_k<<<1536, 256, 0, stream>>>(rw_ih_f, rw_ih_b, aw_ih_f, aw_ih_b,
                                       rb_ih_f, rb_ih_b, ab_ih_f, ab_ih_b,
                                       rw_hh_f, rw_hh_b, aw_hh_f, aw_hh_b,
                                       wrh, wah, wr16, wa16, br, ba);
    conv_k<<<40960, 256, 0, stream>>>(context, options, ctxh, opth);

    // 2. context: gx GEMM (MFMA, DIRECT DMA staging) + GRU per chunk
    for (int c = 0; c < CC; c++) {
        const int Mc = bc * 512;   // always % 64 == 0
        hgemm_k<false, false, true, true><<<dim3(12, Mc / 64, 1), 256, 0, stream>>>(
            ctxh + (size_t)c * Mc * 320, nullptr, wrh, br, POOL,
            Mc, 768, 320, 320, 320, 768, 0, 0, 1, 0);
        gru_rec_k<64><<<2 * bc, 512, 0, stream>>>(
            POOL, wr16, rb_hh_f, rb_hh_b,
            couts + (size_t)c * Mc * 256, ctxhf + (size_t)c * bc * 256, 512);
    }

    // 3. ctx row inverse norms
    rowinv_k<<<32768, 256, 0, stream>>>(couts, rinvc);

    // 4. options: per chunk pipeline
    for (int o = 0; o < OC; o++) {
        const int base = o * sc;
        const int Mo = sc * 50;
        const bool modir = (Mo % 64) == 0;
        const _Float16* ctxB = couts + (size_t)(base / 10) * 131072;

        // 4a. opt gx (MFMA) -> POOL[0 .. sc*38400 halfs)
        if (modir)
            hgemm_k<false, false, true, true><<<dim3(12, Mo / 64, 1), 256, 0, stream>>>(
                opth + (size_t)base * 50 * 320, nullptr, wrh, br, POOL,
                Mo, 768, 320, 320, 320, 768, 0, 0, 1, 0);
        else
            hgemm_k<false, false, true, false><<<dim3(12, (Mo + 63) / 64, 1), 256, 0, stream>>>(
                opth + (size_t)base * 50 * 320, nullptr, wrh, br, POOL,
                Mo, 768, 320, 320, 320, 768, 0, 0, 1, 0);
        // 4b. opt GRU -> P2H   (opt gx dead after this)
        gru_rec_k<50><<<2 * sc, 512, 0, stream>>>(
            POOL, wr16, rb_hh_f, rb_hh_b, P2H, nullptr, 50);
        // 4c. opt row inverse norms
        rowinv_k<<<Mo, 256, 0, stream>>>(P2H, rinvo + (size_t)base * 50);
        // 4d. raw scores (MFMA, NT, batched): ATT = P2H @ ctxB^T
        hgemm_k<false, false, false, false><<<dim3(8, 1, sc), 256, 0, stream>>>(
            P2H, nullptr, ctxB, nullptr, ATT,
            50, 512, 256, 256, 256, 512, 12800, 131072, 10, 25600);
        // 4e. fused cosine scaling + softmax (fp16 in-place)
        att_softmax_k<<<Mo, 256, 0, stream>>>(ATT, rinvo + (size_t)base * 50,
                                              rinvc, base);
        // 4f. att_opt (MFMA, NN via transpose-stage): P3H = ATT @ ctxB
        hgemm_k<true, false, false, false><<<dim3(4, 1, sc), 256, 0, stream>>>(
            ATT, nullptr, ctxB, nullptr, P3H,
            50, 256, 512, 512, 256, 256, 25600, 131072, 10, 12800);
        // 4g. attn gx (MFMA, split-A K=512) -> POOL[0 ..) (opt-gx region, dead)
        if (modir)
            hgemm_k<false, true, true, true><<<dim3(12, Mo / 64, 1), 256, 0, stream>>>(
                P3H, P2H, wah, ba, POOL,
                Mo, 768, 512, 256, 512, 768, 0, 0, 1, 0);
        else
            hgemm_k<false, true, true, false><<<dim3(12, (Mo + 63) / 64, 1), 256, 0, stream>>>(
                P3H, P2H, wah, ba, POOL,
                Mo, 768, 512, 256, 512, 768, 0, 0, 1, 0);
        // 4h. attn GRU -> ao_h
        gru_rec_k<50><<<2 * sc, 512, 0, stream>>>(
            POOL, wa16, ab_hh_f, ab_hh_b, nullptr, aohf + (size_t)base * 256, 50);
    }

    // 5. cosine logits + final softmax
    logits_k<<<640, 256, 0, stream>>>(ctxhf, aohf, logits);
    soft10_k<<<64, 64, 0, stream>>>(logits, (float*)d_out);
}

// Round 13
// 1038.217 us; speedup vs baseline: 1.0385x; 1.0385x over previous
//
#include <hip/hip_runtime.h>
#include <math.h>

#define EPS 1e-8f

typedef _Float16 h2_t __attribute__((ext_vector_type(2)));
typedef _Float16 half8 __attribute__((ext_vector_type(8)));
typedef float f32x4 __attribute__((ext_vector_type(4)));

__device__ __forceinline__ float fsig(float x)  { return 1.0f / (1.0f + __expf(-x)); }
__device__ __forceinline__ float ftanh(float x) { return 1.0f - 2.0f / (1.0f + __expf(2.0f * x)); }

// Wave-level 16B/lane global->LDS DMA (no VGPR round trip). LDS dest is
// wave-uniform base + lane*16; global src is per-lane.
__device__ __forceinline__ void gload16(const _Float16* g, _Float16* lds) {
    __builtin_amdgcn_global_load_lds(
        (const __attribute__((address_space(1))) void*)g,
        (__attribute__((address_space(3))) void*)lds, 16, 0, 0);
}

// Quad butterfly sum via DPP (VALU pipe) -- all 4 lanes get the full sum.
__device__ __forceinline__ float qsum4(float x) {
    int y1 = __builtin_amdgcn_update_dpp(
        0, __builtin_bit_cast(int, x), 0xB1, 0xF, 0xF, true);   // quad_perm [1,0,3,2]
    float s1 = x + __builtin_bit_cast(float, y1);
    int y2 = __builtin_amdgcn_update_dpp(
        0, __builtin_bit_cast(int, s1), 0x4E, 0xF, 0xF, true);  // quad_perm [2,3,0,1]
    return s1 + __builtin_bit_cast(float, y2);
}

// ---------------------------------------------------------------------------
// Weight prep: W_ih stacks -> fp16 [768,320pad]/[768,512]; W_hh -> fp16
// [2][384][128]; biases fp32.
// ---------------------------------------------------------------------------
__global__ __launch_bounds__(256) void prep_w_k(
    const float* __restrict__ rwf, const float* __restrict__ rwb,
    const float* __restrict__ awf, const float* __restrict__ awb,
    const float* __restrict__ rbf, const float* __restrict__ rbb,
    const float* __restrict__ abf, const float* __restrict__ abb,
    const float* __restrict__ rhf, const float* __restrict__ rhb,
    const float* __restrict__ ahf, const float* __restrict__ ahb,
    _Float16* __restrict__ wrh, _Float16* __restrict__ wah,
    _Float16* __restrict__ wr16, _Float16* __restrict__ wa16,
    float* __restrict__ br, float* __restrict__ ba)
{
    int idx = blockIdx.x * 256 + threadIdx.x;
    if (idx < 768 * 320) {
        int g = idx / 320, k = idx % 320;
        float v = 0.f;
        if (k < 300) v = (g < 384) ? rwf[g * 300 + k] : rwb[(g - 384) * 300 + k];
        wrh[idx] = (_Float16)v;
    }
    if (idx < 768 * 512) {
        int g = idx / 512, k = idx % 512;
        wah[idx] = (_Float16)((g < 384) ? awf[g * 512 + k] : awb[(g - 384) * 512 + k]);
    }
    if (idx < 2 * 384 * 128) {
        int d = idx / 49152, r = idx % 49152;
        wr16[idx] = (_Float16)(d ? rhb[r] : rhf[r]);
        wa16[idx] = (_Float16)(d ? ahb[r] : ahf[r]);
    }
    if (idx < 768) {
        br[idx] = (idx < 384) ? rbf[idx] : rbb[idx - 384];
        ba[idx] = (idx < 384) ? abf[idx] : abb[idx - 384];
    }
}

// ---------------------------------------------------------------------------
// Input conversion fp32 -> fp16 (K padded 300->320), VECTORIZED: one half8
// store per 8-elem chunk; f32x4 loads on the fast path (alignment holds:
// (300r + k0)*4 % 16 == 0 for k0 % 8 == 0). Slow path only for the 3
// boundary chunks per row (k0 = 296/304/312).
// ---------------------------------------------------------------------------
__global__ __launch_bounds__(256) void conv_k(
    const float* __restrict__ ctx, const float* __restrict__ opt,
    _Float16* __restrict__ ctxh, _Float16* __restrict__ opth)
{
    const long NCTX = 32768L * 40;            // chunks of 8 in padded rows
    const long NTOT = NCTX + 32000L * 40;
    for (long c = (long)blockIdx.x * 256 + threadIdx.x; c < NTOT;
         c += (long)gridDim.x * 256) {
        const bool isctx = c < NCTX;
        const long cc = isctx ? c : c - NCTX;
        const int r  = (int)(cc / 40);
        const int k0 = (int)(cc % 40) * 8;
        const float* src = (isctx ? ctx : opt) + (size_t)r * 300;
        _Float16*    dst = (isctx ? ctxh : opth) + (size_t)r * 320 + k0;
        half8 hv;
        if (k0 + 8 <= 300) {
            f32x4 f0 = *(const f32x4*)(src + k0);
            f32x4 f1 = *(const f32x4*)(src + k0 + 4);
#pragma unroll
            for (int e = 0; e < 4; e++) {
                hv[e]     = (_Float16)f0[e];
                hv[e + 4] = (_Float16)f1[e];
            }
        } else {
#pragma unroll
            for (int e = 0; e < 8; e++) {
                const int k = k0 + e;
                hv[e] = (k < 300) ? (_Float16)src[k] : (_Float16)0.f;
            }
        }
        *(half8*)dst = hv;
    }
}

// ---------------------------------------------------------------------------
// fp16 MFMA GEMM, 64x64 tile, BK=64, 256 threads = 4 waves (2x2 of 32x32).
// C[z] = A[z] * B[z/bdiv]^T + bias, fp32 accumulate, fp16 out.
// TRBS:   B given as [K][N] row-major -> transpose-stage into LDS.
// SPLITA: A = [A|A2] along K (each lda wide, fp16).
// DIRECT: stage via global_load_lds (wave DMA, 16B/lane) -- requires
//         M % 64 == 0 (no predication) and !TRBS.
// K must be a multiple of 64 (320/256/512 all are).
// ---------------------------------------------------------------------------
template <bool TRBS, bool SPLITA, bool HASBIAS, bool DIRECT>
__global__ __launch_bounds__(256, 4) void hgemm_k(
    const _Float16* __restrict__ A, const _Float16* __restrict__ A2,
    const _Float16* __restrict__ B, const float* __restrict__ bias,
    _Float16* __restrict__ C, int M, int N, int K,
    int lda, int ldb, int ldc, long sA, long sB, int bdiv, long sC)
{
    static_assert(!(DIRECT && TRBS), "DIRECT requires NT B layout");
    const int jn = blockIdx.x * 64;
    const int im = blockIdx.y * 64;
    const int z  = blockIdx.z;
    const _Float16* Bb = B + (size_t)(z / bdiv) * sB;
    _Float16* Cb = C + (size_t)z * sC;

    __shared__ __align__(16) _Float16 As[64 * 64];
    __shared__ __align__(16) _Float16 Bs[64 * 64];

    const int tid  = threadIdx.x;
    const int arow = tid >> 2;          // 0..63
    const int akof = (tid & 3) * 8;     // 0,8,16,24
    const int lane = tid & 63;
    const int wv   = tid >> 6;          // 0..3
    const int wm   = (wv & 1) * 32;
    const int wn   = (wv >> 1) * 32;
    const int fm   = lane & 15;
    const int quad = lane >> 4;

    f32x4 acc[2][2];
#pragma unroll
    for (int a = 0; a < 2; a++)
#pragma unroll
        for (int b = 0; b < 2; b++) acc[a][b] = (f32x4)0.f;

    for (int k0 = 0; k0 < K; k0 += 64) {
        if constexpr (DIRECT) {
            const int r8 = lane >> 3;
            const int kg = k0 + (lane & 7) * 8;
#pragma unroll
            for (int hh = 0; hh < 2; hh++) {
                const int rb = 8 * (wv + 4 * hh);
                const _Float16* gA;
                if constexpr (SPLITA) {
                    const _Float16* Ah  = A  + (size_t)z * sA;
                    const _Float16* A2h = A2 + (size_t)z * sA;
                    gA = (kg < 256)
                        ? (Ah  + (size_t)(im + rb + r8) * lda + kg)
                        : (A2h + (size_t)(im + rb + r8) * lda + (kg - 256));
                } else {
                    gA = A + (size_t)z * sA + (size_t)(im + rb + r8) * lda + kg;
                }
                gload16(gA, &As[rb * 64]);
                gload16(Bb + (size_t)(jn + rb + r8) * ldb + kg, &Bs[rb * 64]);
            }
        } else {
            // ---- A tile: 64 rows x 64 k (2 half8 per thread)
            {
                const int row = im + arow;
#pragma unroll
                for (int hh = 0; hh < 2; hh++) {
                    half8 av = (half8)(_Float16)0.f;
                    const int kg = k0 + akof + 32 * hh;
                    if (row < M) {
                        if constexpr (SPLITA) {
                            const _Float16* Ah  = A + (size_t)z * sA;
                            const _Float16* A2h = A2 + (size_t)z * sA;
                            const _Float16* ap = (kg < 256)
                                ? (Ah + (size_t)row * lda + kg)
                                : (A2h + (size_t)row * lda + (kg - 256));
                            av = *(const half8*)ap;
                        } else {
                            av = *(const half8*)(A + (size_t)z * sA + (size_t)row * lda + kg);
                        }
                    }
                    *(half8*)&As[arow * 64 + akof + 32 * hh] = av;
                }
            }
            // ---- B tile
            if constexpr (!TRBS) {          // B [N][K] rm (NT)
#pragma unroll
                for (int hh = 0; hh < 2; hh++) {
                    half8 bv = *(const half8*)(Bb + (size_t)(jn + arow) * ldb
                                               + k0 + akof + 32 * hh);
                    *(half8*)&Bs[arow * 64 + akof + 32 * hh] = bv;
                }
            } else {                        // B [K][N] rm -> LDS [n][k]
                const int kk = tid >> 3, noff = (tid & 7) * 8;
                half8 bv0 = *(const half8*)(Bb + (size_t)(k0 + kk) * ldb + jn + noff);
                half8 bv1 = *(const half8*)(Bb + (size_t)(k0 + kk + 32) * ldb + jn + noff);
#pragma unroll
                for (int e = 0; e < 8; e++) {
                    Bs[(noff + e) * 64 + kk]      = bv0[e];
                    Bs[(noff + e) * 64 + kk + 32] = bv1[e];
                }
            }
        }
        __syncthreads();

        const _Float16* Asp = As + (wm + fm) * 64 + quad * 8;
        const _Float16* Bsp = Bs + (wn + fm) * 64 + quad * 8;
#pragma unroll
        for (int kh = 0; kh < 64; kh += 32) {
            half8 a0 = *(const half8*)(Asp + kh);
            half8 a1 = *(const half8*)(Asp + 16 * 64 + kh);
            half8 b0 = *(const half8*)(Bsp + kh);
            half8 b1 = *(const half8*)(Bsp + 16 * 64 + kh);
            acc[0][0] = __builtin_amdgcn_mfma_f32_16x16x32_f16(a0, b0, acc[0][0], 0, 0, 0);
            acc[0][1] = __builtin_amdgcn_mfma_f32_16x16x32_f16(a0, b1, acc[0][1], 0, 0, 0);
            acc[1][0] = __builtin_amdgcn_mfma_f32_16x16x32_f16(a1, b0, acc[1][0], 0, 0, 0);
            acc[1][1] = __builtin_amdgcn_mfma_f32_16x16x32_f16(a1, b1, acc[1][1], 0, 0, 0);
        }
        __syncthreads();
    }

#pragma unroll
    for (int tm = 0; tm < 2; tm++) {
#pragma unroll
        for (int tn = 0; tn < 2; tn++) {
            const int col  = jn + wn + tn * 16 + fm;
            const int row0 = im + wm + tm * 16 + quad * 4;
            const float bv = HASBIAS ? bias[col] : 0.f;
#pragma unroll
            for (int r = 0; r < 4; r++) {
                const int row = row0 + r;
                if (DIRECT || row < M)
                    Cb[(size_t)row * ldc + col] = (_Float16)(acc[tm][tn][r] + bv);
            }
        }
    }
}

// ---------------------------------------------------------------------------
// BM=128 variant of the DIRECT-DMA GEMM: 128x64 tile, BK=64, 4 waves. Per
// K-step per wave: 16 MFMA vs 12 ds_read_b128 + 6 DMA (vs 8:8:4 in 64-tile)
// -- doubles the MFMA:stage ratio and halves B traffic + barriers per FLOP.
// Requires M % 128 == 0; used for the big gx GEMMs.
// ---------------------------------------------------------------------------
template <bool SPLITA, bool HASBIAS>
__global__ __launch_bounds__(256, 4) void hgemm2_k(
    const _Float16* __restrict__ A, const _Float16* __restrict__ A2,
    const _Float16* __restrict__ B, const float* __restrict__ bias,
    _Float16* __restrict__ C, int M, int N, int K,
    int lda, int ldb, int ldc, long sA, long sB, int bdiv, long sC)
{
    const int jn = blockIdx.x * 64;
    const int im = blockIdx.y * 128;
    const int z  = blockIdx.z;
    const _Float16* Bb = B + (size_t)(z / bdiv) * sB;
    _Float16* Cb = C + (size_t)z * sC;

    __shared__ __align__(16) _Float16 As[128 * 64];
    __shared__ __align__(16) _Float16 Bs[64 * 64];

    const int tid  = threadIdx.x;
    const int lane = tid & 63;
    const int wv   = tid >> 6;
    const int wm   = (wv & 1) * 32;
    const int wn   = (wv >> 1) * 32;
    const int fm   = lane & 15;
    const int quad = lane >> 4;

    f32x4 acc[2][2][2];   // [mh][tm][tn]
#pragma unroll
    for (int m = 0; m < 2; m++)
#pragma unroll
        for (int a = 0; a < 2; a++)
#pragma unroll
            for (int b = 0; b < 2; b++) acc[m][a][b] = (f32x4)0.f;

    for (int k0 = 0; k0 < K; k0 += 64) {
        const int r8 = lane >> 3;
        const int kg = k0 + (lane & 7) * 8;
        // A: 4 chunks of 8 rows per wave -> rows 0..127
#pragma unroll
        for (int hh = 0; hh < 4; hh++) {
            const int rb = 8 * (wv + 4 * hh);
            const _Float16* gA;
            if constexpr (SPLITA) {
                const _Float16* Ah  = A  + (size_t)z * sA;
                const _Float16* A2h = A2 + (size_t)z * sA;
                gA = (kg < 256)
                    ? (Ah  + (size_t)(im + rb + r8) * lda + kg)
                    : (A2h + (size_t)(im + rb + r8) * lda + (kg - 256));
            } else {
                gA = A + (size_t)z * sA + (size_t)(im + rb + r8) * lda + kg;
            }
            gload16(gA, &As[rb * 64]);
        }
        // B: 2 chunks of 8 rows per wave -> rows 0..63
#pragma unroll
        for (int hh = 0; hh < 2; hh++) {
            const int rb = 8 * (wv + 4 * hh);
            gload16(Bb + (size_t)(jn + rb + r8) * ldb + kg, &Bs[rb * 64]);
        }
        __syncthreads();

        const _Float16* Bsp = Bs + (wn + fm) * 64 + quad * 8;
#pragma unroll
        for (int kh = 0; kh < 64; kh += 32) {
            half8 b0 = *(const half8*)(Bsp + kh);
            half8 b1 = *(const half8*)(Bsp + 16 * 64 + kh);
#pragma unroll
            for (int mh = 0; mh < 2; mh++) {
                const _Float16* Asp = As + (mh * 64 + wm + fm) * 64 + quad * 8;
                half8 a0 = *(const half8*)(Asp + kh);
                half8 a1 = *(const half8*)(Asp + 16 * 64 + kh);
                acc[mh][0][0] = __builtin_amdgcn_mfma_f32_16x16x32_f16(a0, b0, acc[mh][0][0], 0, 0, 0);
                acc[mh][0][1] = __builtin_amdgcn_mfma_f32_16x16x32_f16(a0, b1, acc[mh][0][1], 0, 0, 0);
                acc[mh][1][0] = __builtin_amdgcn_mfma_f32_16x16x32_f16(a1, b0, acc[mh][1][0], 0, 0, 0);
                acc[mh][1][1] = __builtin_amdgcn_mfma_f32_16x16x32_f16(a1, b1, acc[mh][1][1], 0, 0, 0);
            }
        }
        __syncthreads();
    }

#pragma unroll
    for (int mh = 0; mh < 2; mh++)
#pragma unroll
        for (int tm = 0; tm < 2; tm++)
#pragma unroll
            for (int tn = 0; tn < 2; tn++) {
                const int col  = jn + wn + tn * 16 + fm;
                const int row0 = im + mh * 64 + wm + tm * 16 + quad * 4;
                const float bv = HASBIAS ? bias[col] : 0.f;
#pragma unroll
                for (int r = 0; r < 4; r++)
                    Cb[(size_t)(row0 + r) * ldc + col] =
                        (_Float16)(acc[mh][tm][tn][r] + bv);
            }
}

// ---------------------------------------------------------------------------
// GRU recurrence v15 (R9, verified: ctx 307us, absmax 4.88e-4) -- EXACT
// revert (R12's gxs-hoist was mildly negative). Step ~1440 cyc is floored
// by the cross-wave LDS write->barrier->read turnaround + transcendental
// chain (R2 MFMA-GRU and R9 fdot-GRU both land here despite 8x different
// LDS instr counts) -- accepted as structural for this decomposition.
// ---------------------------------------------------------------------------
template <int TCMAX>
__global__ __launch_bounds__(512, 2) void gru_rec_k(
    const _Float16* __restrict__ gx,
    const _Float16* __restrict__ whh16,   // [2][384][128] fp16, dir-major
    const float* __restrict__ bhh_f, const float* __restrict__ bhh_b,
    _Float16* __restrict__ outs_h, float* __restrict__ hfin, int L)
{
    const int dir = blockIdx.x & 1;
    const int s   = blockIdx.x >> 1;
    const int t   = threadIdx.x;
    const int w   = t >> 6;
    const int l   = t & 63;
    const int i   = w * 16 + (l >> 2);  // output index (one per quad)
    const int kq  = l & 3;              // k-quarter within quad
    const _Float16* Wd = whh16 + (size_t)dir * 49152;
    const float* bh = dir ? bhh_b : bhh_f;

    h2_t w2[3][16];
#pragma unroll
    for (int j = 0; j < 3; j++) {
        const _Float16* Wr = Wd + (size_t)(i + 128 * j) * 128 + 32 * kq;
#pragma unroll
        for (int q = 0; q < 16; q++)
            w2[j][q] = *(const h2_t*)(Wr + 2 * q);
    }
    const float b0 = bh[i], b1 = bh[i + 128], b2 = bh[i + 256];

    __shared__ __align__(16) _Float16 h1[2][128];
    __shared__ __align__(16) _Float16 gxs[TCMAX][384];
    __shared__ __align__(16) _Float16 outb[TCMAX][128];
    if (t < 128) h1[0][t] = (_Float16)0.f;
    float hprev = 0.f;

    constexpr int NST = (TCMAX * 48 + 511) / 512;   // staging chunks/thread
    constexpr int NFL = (TCMAX * 16 + 511) / 512;   // flush chunks/thread

    for (int t0 = 0; t0 < L; t0 += TCMAX) {
        const int Tc = (L - t0 < TCMAX) ? (L - t0) : TCMAX;
        // stage gx tile (Tc*48 half8 chunks over 512 threads)
#pragma unroll
        for (int r = 0; r < NST; r++) {
            const int q = t + 512 * r;
            if (q < Tc * 48) {
                const int j = q / 48, off = (q % 48) * 8;
                const int tt = dir ? (L - 1 - (t0 + j)) : (t0 + j);
                *(half8*)&gxs[j][off] =
                    *(const half8*)(gx + ((size_t)s * L + tt) * 768 + dir * 384 + off);
            }
        }
        __syncthreads();   // drains staging; orders h1 init / prev flush

        for (int j = 0; j < Tc; j++) {
            const int cb = (t0 + j) & 1;
            const h2_t* hp = (const h2_t*)&h1[cb][32 * kq];
            float a0 = 0.f, a1 = 0.f, a2 = 0.f;
#pragma unroll
            for (int q = 0; q < 16; q++) {
                h2_t hq = hp[q];
                a0 = __builtin_amdgcn_fdot2(w2[0][q], hq, a0, false);
                a1 = __builtin_amdgcn_fdot2(w2[1][q], hq, a1, false);
                a2 = __builtin_amdgcn_fdot2(w2[2][q], hq, a2, false);
            }
            a0 = qsum4(a0);
            a1 = qsum4(a1);
            a2 = qsum4(a2);
            const float xc0 = (float)gxs[j][i];
            const float xc1 = (float)gxs[j][i + 128];
            const float xc2 = (float)gxs[j][i + 256];
            const float r  = fsig(xc0 + a0 + b0);
            const float zz = fsig(xc1 + a1 + b1);
            const float n  = ftanh(xc2 + r * (a2 + b2));
            const float hnew = (1.0f - zz) * n + zz * hprev;
            hprev = hnew;
            if (kq == 0) {
                h1[cb ^ 1][i] = (_Float16)hnew;
                outb[j][i]    = (_Float16)hnew;
            }
            __syncthreads();
        }

        // bulk flush outs tile (Tc*16 half8 chunks)
        if (outs_h) {
#pragma unroll
            for (int r = 0; r < NFL; r++) {
                const int q = t + 512 * r;
                if (q < Tc * 16) {
                    const int j = q / 16, off = (q % 16) * 8;
                    const int tt = dir ? (L - 1 - (t0 + j)) : (t0 + j);
                    *(half8*)(outs_h + ((size_t)s * L + tt) * 256 + dir * 128 + off) =
                        *(const half8*)&outb[j][off];
                }
            }
        }
    }
    if (hfin && kq == 0) hfin[(size_t)s * 256 + dir * 128 + i] = hprev;
}

// ---------------------------------------------------------------------------
// Row inverse norms over fp16 rows of 256: one 64-lane wave per row, 4 halfs
// per lane, shfl reduce -- no LDS, no barriers (was 256 thr + 2 barriers).
// ---------------------------------------------------------------------------
__global__ __launch_bounds__(64) void rowinv_k(const _Float16* __restrict__ x,
                                               float* __restrict__ rinv)
{
    const int row = blockIdx.x;
    const _Float16* p = x + (size_t)row * 256 + threadIdx.x * 4;
    const h2_t v0 = *(const h2_t*)p;
    const h2_t v1 = *(const h2_t*)(p + 2);
    float ss = (float)v0[0] * (float)v0[0] + (float)v0[1] * (float)v0[1]
             + (float)v1[0] * (float)v1[0] + (float)v1[1] * (float)v1[1];
#pragma unroll
    for (int o = 32; o > 0; o >>= 1) ss += __shfl_down(ss, o);
    if (threadIdx.x == 0)
        rinv[row] = 1.0f / fmaxf(sqrtf(ss), EPS);
}

// ---------------------------------------------------------------------------
// Fused cosine-scale + softmax (fp16 in/out, 512 positions).
// ---------------------------------------------------------------------------
__global__ __launch_bounds__(256) void att_softmax_k(
    _Float16* __restrict__ att, const float* __restrict__ rinv_opt_l,
    const float* __restrict__ rinv_ctx, int sbase)
{
    const int row = blockIdx.x;
    const int b = (sbase + row / 50) / 10;
    _Float16* p = att + (size_t)row * 512;
    const float* rc = rinv_ctx + b * 512;
    const float sA = rinv_opt_l[row];
    const int t = threadIdx.x;

    float v0 = (float)p[t]       * (sA * rc[t]);
    float v1 = (float)p[t + 256] * (sA * rc[t + 256]);

    __shared__ float red[4];
    float m = fmaxf(v0, v1);
#pragma unroll
    for (int o = 32; o > 0; o >>= 1) m = fmaxf(m, __shfl_down(m, o));
    if ((t & 63) == 0) red[t >> 6] = m;
    __syncthreads();
    m = fmaxf(fmaxf(red[0], red[1]), fmaxf(red[2], red[3]));
    float e0 = __expf(v0 - m), e1 = __expf(v1 - m);
    float ssum = e0 + e1;
#pragma unroll
    for (int o = 32; o > 0; o >>= 1) ssum += __shfl_down(ssum, o);
    __syncthreads();
    if ((t & 63) == 0) red[t >> 6] = ssum;
    __syncthreads();
    float inv = 1.0f / (red[0] + red[1] + red[2] + red[3]);
    p[t]       = (_Float16)(e0 * inv);
    p[t + 256] = (_Float16)(e1 * inv);
}

// ---------------------------------------------------------------------------
// logits[s] = cosine(ctx_h[s/10], ao_h[s])
// ---------------------------------------------------------------------------
__global__ __launch_bounds__(256) void logits_k(const float* __restrict__ ch,
                                                const float* __restrict__ ah,
                                                float* __restrict__ logits)
{
    const int s = blockIdx.x;
    const int b = s / 10;
    const int t = threadIdx.x;
    float a = ch[b * 256 + t];
    float c = ah[(size_t)s * 256 + t];
    float num = a * c, na = a * a, nc = c * c;
#pragma unroll
    for (int o = 32; o > 0; o >>= 1) {
        num += __shfl_down(num, o);
        na  += __shfl_down(na,  o);
        nc  += __shfl_down(nc,  o);
    }
    __shared__ float pn[4], pa[4], pc[4];
    if ((t & 63) == 0) { pn[t >> 6] = num; pa[t >> 6] = na; pc[t >> 6] = nc; }
    __syncthreads();
    if (t == 0) {
        float sn = pn[0] + pn[1] + pn[2] + pn[3];
        float sa = pa[0] + pa[1] + pa[2] + pa[3];
        float sc = pc[0] + pc[1] + pc[2] + pc[3];
        logits[s] = sn / (fmaxf(sqrtf(sa), EPS) * fmaxf(sqrtf(sc), EPS));
    }
}

// ---------------------------------------------------------------------------
__global__ __launch_bounds__(64) void soft10_k(const float* __restrict__ logits,
                                               float* __restrict__ out)
{
    const int b = blockIdx.x;
    const int t = threadIdx.x;
    __shared__ float v[10];
    if (t < 10) v[t] = logits[b * 10 + t];
    __syncthreads();
    if (t < 10) {
        float m = v[0];
#pragma unroll
        for (int i = 1; i < 10; i++) m = fmaxf(m, v[i]);
        float ssum = 0.f;
#pragma unroll
        for (int i = 0; i < 10; i++) ssum += __expf(v[i] - m);
        out[b * 10 + t] = __expf(v[t] - m) / ssum;
    }
}

// ---------------------------------------------------------------------------
extern "C" void kernel_launch(void* const* d_in, const int* in_sizes, int n_in,
                              void* d_out, int out_size, void* d_ws, size_t ws_size,
                              hipStream_t stream)
{
    const float* context = (const float*)d_in[0];
    const float* options = (const float*)d_in[2];
    const float* rw_ih_f = (const float*)d_in[4];
    const float* rw_hh_f = (const float*)d_in[5];
    const float* rb_ih_f = (const float*)d_in[6];
    const float* rb_hh_f = (const float*)d_in[7];
    const float* rw_ih_b = (const float*)d_in[8];
    const float* rw_hh_b = (const float*)d_in[9];
    const float* rb_ih_b = (const float*)d_in[10];
    const float* rb_hh_b = (const float*)d_in[11];
    const float* aw_ih_f = (const float*)d_in[12];
    const float* aw_hh_f = (const float*)d_in[13];
    const float* ab_ih_f = (const float*)d_in[14];
    const float* ab_hh_f = (const float*)d_in[15];
    const float* aw_ih_b = (const float*)d_in[16];
    const float* aw_hh_b = (const float*)d_in[17];
    const float* ab_ih_b = (const float*)d_in[18];
    const float* ab_hh_b = (const float*)d_in[19];

    // --- chunk config. persist(fl) = 15,222,144 (~60.9 MB).
    //     ATT lives INSIDE the POOL (disjoint lifetimes). pool =
    //     max(bc*196608, sc*32000); extras = 2*sc*6400 (P2H,P3H).
    const size_t persist = 15222144;
    static const int cands[6][2] = {{1,2},{1,4},{2,4},{2,8},{4,16},{8,16}};
    int CC = 8, OC = 16;
    for (int idx = 0; idx < 6; idx++) {
        size_t bc_ = 64 / cands[idx][0], sc_ = 640 / cands[idx][1];
        size_t p = bc_ * 196608;
        if (sc_ * 32000 > p) p = sc_ * 32000;
        if ((persist + p + 2 * sc_ * 6400) * 4 <= ws_size) {
            CC = cands[idx][0]; OC = cands[idx][1]; break;
        }
    }
    const int bc = 64 / CC;
    const int sc = 640 / OC;
    size_t poolsz = (size_t)bc * 196608;
    if ((size_t)sc * 32000 > poolsz) poolsz = (size_t)sc * 32000;

    float* ws = (float*)d_ws;
    size_t off = 0;
    _Float16* wrh   = (_Float16*)(ws + off); off += 122880;   // [768][320] h
    float*    br    = ws + off;              off += 768;
    _Float16* wah   = (_Float16*)(ws + off); off += 196608;   // [768][512] h
    float*    ba    = ws + off;              off += 768;
    _Float16* wr16  = (_Float16*)(ws + off); off += 49152;    // [2][384][128] h
    _Float16* wa16  = (_Float16*)(ws + off); off += 49152;    // [2][384][128] h
    _Float16* couts = (_Float16*)(ws + off); off += 4194304;  // [64*512][256] h
    float*    ctxhf = ws + off;              off += 16384;    // ctx h_fin
    float*    aohf  = ws + off;              off += 163840;   // ao h_fin
    float*    logits= ws + off;              off += 640;
    float*    rinvc = ws + off;              off += 32768;
    float*    rinvo = ws + off;              off += 32000;
    _Float16* ctxh  = (_Float16*)(ws + off); off += 5242880;  // [32768][320] h
    _Float16* opth  = (_Float16*)(ws + off); off += 5120000;  // [32000][320] h
    _Float16* POOL  = (_Float16*)(ws + off); off += poolsz;   // gx pool (+ATT)
    _Float16* P2H   = (_Float16*)(ws + off); off += (size_t)sc * 6400;
    _Float16* P3H   = (_Float16*)(ws + off); off += (size_t)sc * 6400;
    _Float16* ATT   = POOL + (size_t)sc * 38400;  // halfs offset (= sc*19200 fl)

    // 1. weights -> fp16; inputs -> fp16 (padded K=320)
    prep_w_k<<<1536, 256, 0, stream>>>(rw_ih_f, rw_ih_b, aw_ih_f, aw_ih_b,
                                       rb_ih_f, rb_ih_b, ab_ih_f, ab_ih_b,
                                       rw_hh_f, rw_hh_b, aw_hh_f, aw_hh_b,
                                       wrh, wah, wr16, wa16, br, ba);
    conv_k<<<4096, 256, 0, stream>>>(context, options, ctxh, opth);

    // 2. context: gx GEMM (MFMA, 128-tile DIRECT DMA) + GRU per chunk
    for (int c = 0; c < CC; c++) {
        const int Mc = bc * 512;   // always % 128 == 0
        hgemm2_k<false, true><<<dim3(12, Mc / 128, 1), 256, 0, stream>>>(
            ctxh + (size_t)c * Mc * 320, nullptr, wrh, br, POOL,
            Mc, 768, 320, 320, 320, 768, 0, 0, 1, 0);
        gru_rec_k<64><<<2 * bc, 512, 0, stream>>>(
            POOL, wr16, rb_hh_f, rb_hh_b,
            couts + (size_t)c * Mc * 256, ctxhf + (size_t)c * bc * 256, 512);
    }

    // 3. ctx row inverse norms (1 wave per row)
    rowinv_k<<<32768, 64, 0, stream>>>(couts, rinvc);

    // 4. options: per chunk pipeline
    for (int o = 0; o < OC; o++) {
        const int base = o * sc;
        const int Mo = sc * 50;
        const _Float16* ctxB = couts + (size_t)(base / 10) * 131072;

        // 4a. opt gx (MFMA) -> POOL[0 .. sc*38400 halfs)
        if ((Mo % 128) == 0)
            hgemm2_k<false, true><<<dim3(12, Mo / 128, 1), 256, 0, stream>>>(
                opth + (size_t)base * 50 * 320, nullptr, wrh, br, POOL,
                Mo, 768, 320, 320, 320, 768, 0, 0, 1, 0);
        else if ((Mo % 64) == 0)
            hgemm_k<false, false, true, true><<<dim3(12, Mo / 64, 1), 256, 0, stream>>>(
                opth + (size_t)base * 50 * 320, nullptr, wrh, br, POOL,
                Mo, 768, 320, 320, 320, 768, 0, 0, 1, 0);
        else
            hgemm_k<false, false, true, false><<<dim3(12, (Mo + 63) / 64, 1), 256, 0, stream>>>(
                opth + (size_t)base * 50 * 320, nullptr, wrh, br, POOL,
                Mo, 768, 320, 320, 320, 768, 0, 0, 1, 0);
        // 4b. opt GRU -> P2H   (opt gx dead after this)
        gru_rec_k<50><<<2 * sc, 512, 0, stream>>>(
            POOL, wr16, rb_hh_f, rb_hh_b, P2H, nullptr, 50);
        // 4c. opt row inverse norms (1 wave per row)
        rowinv_k<<<Mo, 64, 0, stream>>>(P2H, rinvo + (size_t)base * 50);
        // 4d. raw scores (MFMA, NT, batched): ATT = P2H @ ctxB^T
        hgemm_k<false, false, false, false><<<dim3(8, 1, sc), 256, 0, stream>>>(
            P2H, nullptr, ctxB, nullptr, ATT,
            50, 512, 256, 256, 256, 512, 12800, 131072, 10, 25600);
        // 4e. fused cosine scaling + softmax (fp16 in-place)
        att_softmax_k<<<Mo, 256, 0, stream>>>(ATT, rinvo + (size_t)base * 50,
                                              rinvc, base);
        // 4f. att_opt (MFMA, NN via transpose-stage): P3H = ATT @ ctxB
        hgemm_k<true, false, false, false><<<dim3(4, 1, sc), 256, 0, stream>>>(
            ATT, nullptr, ctxB, nullptr, P3H,
            50, 256, 512, 512, 256, 256, 25600, 131072, 10, 12800);
        // 4g. attn gx (MFMA, split-A K=512) -> POOL[0 ..) (opt-gx region, dead)
        if ((Mo % 128) == 0)
            hgemm2_k<true, true><<<dim3(12, Mo / 128, 1), 256, 0, stream>>>(
                P3H, P2H, wah, ba, POOL,
                Mo, 768, 512, 256, 512, 768, 0, 0, 1, 0);
        else if ((Mo % 64) == 0)
            hgemm_k<false, true, true, true><<<dim3(12, Mo / 64, 1), 256, 0, stream>>>(
                P3H, P2H, wah, ba, POOL,
                Mo, 768, 512, 256, 512, 768, 0, 0, 1, 0);
        else
            hgemm_k<false, true, true, false><<<dim3(12, (Mo + 63) / 64, 1), 256, 0, stream>>>(
                P3H, P2H, wah, ba, POOL,
                Mo, 768, 512, 256, 512, 768, 0, 0, 1, 0);
        // 4h. attn GRU -> ao_h
        gru_rec_k<50><<<2 * sc, 512, 0, stream>>>(
            POOL, wa16, ab_hh_f, ab_hh_b, nullptr, aohf + (size_t)base * 256, 50);
    }

    // 5. cosine logits + final softmax
    logits_k<<<640, 256, 0, stream>>>(ctxhf, aohf, logits);
    soft10_k<<<64, 64, 0, stream>>>(logits, (float*)d_out);
}

// Round 14
// 1021.290 us; speedup vs baseline: 1.0557x; 1.0166x over previous
//
#include <hip/hip_runtime.h>
#include <math.h>

#define EPS 1e-8f

typedef _Float16 h2_t __attribute__((ext_vector_type(2)));
typedef _Float16 half8 __attribute__((ext_vector_type(8)));
typedef float f32x4 __attribute__((ext_vector_type(4)));

__device__ __forceinline__ float fsig(float x)  { return 1.0f / (1.0f + __expf(-x)); }
__device__ __forceinline__ float ftanh(float x) { return 1.0f - 2.0f / (1.0f + __expf(2.0f * x)); }

// Wave-level 16B/lane global->LDS DMA (no VGPR round trip). LDS dest is
// wave-uniform base + lane*16; global src is per-lane.
__device__ __forceinline__ void gload16(const _Float16* g, _Float16* lds) {
    __builtin_amdgcn_global_load_lds(
        (const __attribute__((address_space(1))) void*)g,
        (__attribute__((address_space(3))) void*)lds, 16, 0, 0);
}

// Quad butterfly sum via DPP (VALU pipe) -- all 4 lanes get the full sum.
__device__ __forceinline__ float qsum4(float x) {
    int y1 = __builtin_amdgcn_update_dpp(
        0, __builtin_bit_cast(int, x), 0xB1, 0xF, 0xF, true);   // quad_perm [1,0,3,2]
    float s1 = x + __builtin_bit_cast(float, y1);
    int y2 = __builtin_amdgcn_update_dpp(
        0, __builtin_bit_cast(int, s1), 0x4E, 0xF, 0xF, true);  // quad_perm [2,3,0,1]
    return s1 + __builtin_bit_cast(float, y2);
}

// ---------------------------------------------------------------------------
// Weight prep: W_ih stacks -> fp16 [768,320pad]/[768,512]; W_hh -> fp16
// [2][384][128]; biases fp32.
// ---------------------------------------------------------------------------
__global__ __launch_bounds__(256) void prep_w_k(
    const float* __restrict__ rwf, const float* __restrict__ rwb,
    const float* __restrict__ awf, const float* __restrict__ awb,
    const float* __restrict__ rbf, const float* __restrict__ rbb,
    const float* __restrict__ abf, const float* __restrict__ abb,
    const float* __restrict__ rhf, const float* __restrict__ rhb,
    const float* __restrict__ ahf, const float* __restrict__ ahb,
    _Float16* __restrict__ wrh, _Float16* __restrict__ wah,
    _Float16* __restrict__ wr16, _Float16* __restrict__ wa16,
    float* __restrict__ br, float* __restrict__ ba)
{
    int idx = blockIdx.x * 256 + threadIdx.x;
    if (idx < 768 * 320) {
        int g = idx / 320, k = idx % 320;
        float v = 0.f;
        if (k < 300) v = (g < 384) ? rwf[g * 300 + k] : rwb[(g - 384) * 300 + k];
        wrh[idx] = (_Float16)v;
    }
    if (idx < 768 * 512) {
        int g = idx / 512, k = idx % 512;
        wah[idx] = (_Float16)((g < 384) ? awf[g * 512 + k] : awb[(g - 384) * 512 + k]);
    }
    if (idx < 2 * 384 * 128) {
        int d = idx / 49152, r = idx % 49152;
        wr16[idx] = (_Float16)(d ? rhb[r] : rhf[r]);
        wa16[idx] = (_Float16)(d ? ahb[r] : ahf[r]);
    }
    if (idx < 768) {
        br[idx] = (idx < 384) ? rbf[idx] : rbb[idx - 384];
        ba[idx] = (idx < 384) ? abf[idx] : abb[idx - 384];
    }
}

// ---------------------------------------------------------------------------
// Input conversion fp32 -> fp16 (K padded 300->320), VECTORIZED.
// ---------------------------------------------------------------------------
__global__ __launch_bounds__(256) void conv_k(
    const float* __restrict__ ctx, const float* __restrict__ opt,
    _Float16* __restrict__ ctxh, _Float16* __restrict__ opth)
{
    const long NCTX = 32768L * 40;            // chunks of 8 in padded rows
    const long NTOT = NCTX + 32000L * 40;
    for (long c = (long)blockIdx.x * 256 + threadIdx.x; c < NTOT;
         c += (long)gridDim.x * 256) {
        const bool isctx = c < NCTX;
        const long cc = isctx ? c : c - NCTX;
        const int r  = (int)(cc / 40);
        const int k0 = (int)(cc % 40) * 8;
        const float* src = (isctx ? ctx : opt) + (size_t)r * 300;
        _Float16*    dst = (isctx ? ctxh : opth) + (size_t)r * 320 + k0;
        half8 hv;
        if (k0 + 8 <= 300) {
            f32x4 f0 = *(const f32x4*)(src + k0);
            f32x4 f1 = *(const f32x4*)(src + k0 + 4);
#pragma unroll
            for (int e = 0; e < 4; e++) {
                hv[e]     = (_Float16)f0[e];
                hv[e + 4] = (_Float16)f1[e];
            }
        } else {
#pragma unroll
            for (int e = 0; e < 8; e++) {
                const int k = k0 + e;
                hv[e] = (k < 300) ? (_Float16)src[k] : (_Float16)0.f;
            }
        }
        *(half8*)dst = hv;
    }
}

// ---------------------------------------------------------------------------
// fp16 MFMA GEMM, 64x64 tile, BK=64, 256 threads = 4 waves (2x2 of 32x32).
// C[z] = A[z] * B[z/bdiv]^T + bias, fp32 accumulate, fp16 out.
// TRBS:   B given as [K][N] row-major -> transpose-stage into LDS.
// SPLITA: A = [A|A2] along K (each lda wide, fp16).
// DIRECT: stage via global_load_lds (wave DMA, 16B/lane) -- requires
//         M % 64 == 0 (no predication) and !TRBS.
// ---------------------------------------------------------------------------
template <bool TRBS, bool SPLITA, bool HASBIAS, bool DIRECT>
__global__ __launch_bounds__(256, 4) void hgemm_k(
    const _Float16* __restrict__ A, const _Float16* __restrict__ A2,
    const _Float16* __restrict__ B, const float* __restrict__ bias,
    _Float16* __restrict__ C, int M, int N, int K,
    int lda, int ldb, int ldc, long sA, long sB, int bdiv, long sC)
{
    static_assert(!(DIRECT && TRBS), "DIRECT requires NT B layout");
    const int jn = blockIdx.x * 64;
    const int im = blockIdx.y * 64;
    const int z  = blockIdx.z;
    const _Float16* Bb = B + (size_t)(z / bdiv) * sB;
    _Float16* Cb = C + (size_t)z * sC;

    __shared__ __align__(16) _Float16 As[64 * 64];
    __shared__ __align__(16) _Float16 Bs[64 * 64];

    const int tid  = threadIdx.x;
    const int arow = tid >> 2;          // 0..63
    const int akof = (tid & 3) * 8;     // 0,8,16,24
    const int lane = tid & 63;
    const int wv   = tid >> 6;          // 0..3
    const int wm   = (wv & 1) * 32;
    const int wn   = (wv >> 1) * 32;
    const int fm   = lane & 15;
    const int quad = lane >> 4;

    f32x4 acc[2][2];
#pragma unroll
    for (int a = 0; a < 2; a++)
#pragma unroll
        for (int b = 0; b < 2; b++) acc[a][b] = (f32x4)0.f;

    for (int k0 = 0; k0 < K; k0 += 64) {
        if constexpr (DIRECT) {
            const int r8 = lane >> 3;
            const int kg = k0 + (lane & 7) * 8;
#pragma unroll
            for (int hh = 0; hh < 2; hh++) {
                const int rb = 8 * (wv + 4 * hh);
                const _Float16* gA;
                if constexpr (SPLITA) {
                    const _Float16* Ah  = A  + (size_t)z * sA;
                    const _Float16* A2h = A2 + (size_t)z * sA;
                    gA = (kg < 256)
                        ? (Ah  + (size_t)(im + rb + r8) * lda + kg)
                        : (A2h + (size_t)(im + rb + r8) * lda + (kg - 256));
                } else {
                    gA = A + (size_t)z * sA + (size_t)(im + rb + r8) * lda + kg;
                }
                gload16(gA, &As[rb * 64]);
                gload16(Bb + (size_t)(jn + rb + r8) * ldb + kg, &Bs[rb * 64]);
            }
        } else {
            // ---- A tile
            {
                const int row = im + arow;
#pragma unroll
                for (int hh = 0; hh < 2; hh++) {
                    half8 av = (half8)(_Float16)0.f;
                    const int kg = k0 + akof + 32 * hh;
                    if (row < M) {
                        if constexpr (SPLITA) {
                            const _Float16* Ah  = A + (size_t)z * sA;
                            const _Float16* A2h = A2 + (size_t)z * sA;
                            const _Float16* ap = (kg < 256)
                                ? (Ah + (size_t)row * lda + kg)
                                : (A2h + (size_t)row * lda + (kg - 256));
                            av = *(const half8*)ap;
                        } else {
                            av = *(const half8*)(A + (size_t)z * sA + (size_t)row * lda + kg);
                        }
                    }
                    *(half8*)&As[arow * 64 + akof + 32 * hh] = av;
                }
            }
            // ---- B tile
            if constexpr (!TRBS) {
#pragma unroll
                for (int hh = 0; hh < 2; hh++) {
                    half8 bv = *(const half8*)(Bb + (size_t)(jn + arow) * ldb
                                               + k0 + akof + 32 * hh);
                    *(half8*)&Bs[arow * 64 + akof + 32 * hh] = bv;
                }
            } else {
                const int kk = tid >> 3, noff = (tid & 7) * 8;
                half8 bv0 = *(const half8*)(Bb + (size_t)(k0 + kk) * ldb + jn + noff);
                half8 bv1 = *(const half8*)(Bb + (size_t)(k0 + kk + 32) * ldb + jn + noff);
#pragma unroll
                for (int e = 0; e < 8; e++) {
                    Bs[(noff + e) * 64 + kk]      = bv0[e];
                    Bs[(noff + e) * 64 + kk + 32] = bv1[e];
                }
            }
        }
        __syncthreads();

        const _Float16* Asp = As + (wm + fm) * 64 + quad * 8;
        const _Float16* Bsp = Bs + (wn + fm) * 64 + quad * 8;
#pragma unroll
        for (int kh = 0; kh < 64; kh += 32) {
            half8 a0 = *(const half8*)(Asp + kh);
            half8 a1 = *(const half8*)(Asp + 16 * 64 + kh);
            half8 b0 = *(const half8*)(Bsp + kh);
            half8 b1 = *(const half8*)(Bsp + 16 * 64 + kh);
            acc[0][0] = __builtin_amdgcn_mfma_f32_16x16x32_f16(a0, b0, acc[0][0], 0, 0, 0);
            acc[0][1] = __builtin_amdgcn_mfma_f32_16x16x32_f16(a0, b1, acc[0][1], 0, 0, 0);
            acc[1][0] = __builtin_amdgcn_mfma_f32_16x16x32_f16(a1, b0, acc[1][0], 0, 0, 0);
            acc[1][1] = __builtin_amdgcn_mfma_f32_16x16x32_f16(a1, b1, acc[1][1], 0, 0, 0);
        }
        __syncthreads();
    }

#pragma unroll
    for (int tm = 0; tm < 2; tm++) {
#pragma unroll
        for (int tn = 0; tn < 2; tn++) {
            const int col  = jn + wn + tn * 16 + fm;
            const int row0 = im + wm + tm * 16 + quad * 4;
            const float bv = HASBIAS ? bias[col] : 0.f;
#pragma unroll
            for (int r = 0; r < 4; r++) {
                const int row = row0 + r;
                if (DIRECT || row < M)
                    Cb[(size_t)row * ldc + col] = (_Float16)(acc[tm][tn][r] + bv);
            }
        }
    }
}

// ---------------------------------------------------------------------------
// BM=128 x BN=64 DIRECT-DMA GEMM (R13's hgemm2): kept for M%128==0 when
// N%128 != 0 isn't the case -- still used as fallback tier.
// ---------------------------------------------------------------------------
template <bool SPLITA, bool HASBIAS>
__global__ __launch_bounds__(256, 4) void hgemm2_k(
    const _Float16* __restrict__ A, const _Float16* __restrict__ A2,
    const _Float16* __restrict__ B, const float* __restrict__ bias,
    _Float16* __restrict__ C, int M, int N, int K,
    int lda, int ldb, int ldc, long sA, long sB, int bdiv, long sC)
{
    const int jn = blockIdx.x * 64;
    const int im = blockIdx.y * 128;
    const int z  = blockIdx.z;
    const _Float16* Bb = B + (size_t)(z / bdiv) * sB;
    _Float16* Cb = C + (size_t)z * sC;

    __shared__ __align__(16) _Float16 As[128 * 64];
    __shared__ __align__(16) _Float16 Bs[64 * 64];

    const int tid  = threadIdx.x;
    const int lane = tid & 63;
    const int wv   = tid >> 6;
    const int wm   = (wv & 1) * 32;
    const int wn   = (wv >> 1) * 32;
    const int fm   = lane & 15;
    const int quad = lane >> 4;

    f32x4 acc[2][2][2];   // [mh][tm][tn]
#pragma unroll
    for (int m = 0; m < 2; m++)
#pragma unroll
        for (int a = 0; a < 2; a++)
#pragma unroll
            for (int b = 0; b < 2; b++) acc[m][a][b] = (f32x4)0.f;

    for (int k0 = 0; k0 < K; k0 += 64) {
        const int r8 = lane >> 3;
        const int kg = k0 + (lane & 7) * 8;
#pragma unroll
        for (int hh = 0; hh < 4; hh++) {
            const int rb = 8 * (wv + 4 * hh);
            const _Float16* gA;
            if constexpr (SPLITA) {
                const _Float16* Ah  = A  + (size_t)z * sA;
                const _Float16* A2h = A2 + (size_t)z * sA;
                gA = (kg < 256)
                    ? (Ah  + (size_t)(im + rb + r8) * lda + kg)
                    : (A2h + (size_t)(im + rb + r8) * lda + (kg - 256));
            } else {
                gA = A + (size_t)z * sA + (size_t)(im + rb + r8) * lda + kg;
            }
            gload16(gA, &As[rb * 64]);
        }
#pragma unroll
        for (int hh = 0; hh < 2; hh++) {
            const int rb = 8 * (wv + 4 * hh);
            gload16(Bb + (size_t)(jn + rb + r8) * ldb + kg, &Bs[rb * 64]);
        }
        __syncthreads();

        const _Float16* Bsp = Bs + (wn + fm) * 64 + quad * 8;
#pragma unroll
        for (int kh = 0; kh < 64; kh += 32) {
            half8 b0 = *(const half8*)(Bsp + kh);
            half8 b1 = *(const half8*)(Bsp + 16 * 64 + kh);
#pragma unroll
            for (int mh = 0; mh < 2; mh++) {
                const _Float16* Asp = As + (mh * 64 + wm + fm) * 64 + quad * 8;
                half8 a0 = *(const half8*)(Asp + kh);
                half8 a1 = *(const half8*)(Asp + 16 * 64 + kh);
                acc[mh][0][0] = __builtin_amdgcn_mfma_f32_16x16x32_f16(a0, b0, acc[mh][0][0], 0, 0, 0);
                acc[mh][0][1] = __builtin_amdgcn_mfma_f32_16x16x32_f16(a0, b1, acc[mh][0][1], 0, 0, 0);
                acc[mh][1][0] = __builtin_amdgcn_mfma_f32_16x16x32_f16(a1, b0, acc[mh][1][0], 0, 0, 0);
                acc[mh][1][1] = __builtin_amdgcn_mfma_f32_16x16x32_f16(a1, b1, acc[mh][1][1], 0, 0, 0);
            }
        }
        __syncthreads();
    }

#pragma unroll
    for (int mh = 0; mh < 2; mh++)
#pragma unroll
        for (int tm = 0; tm < 2; tm++)
#pragma unroll
            for (int tn = 0; tn < 2; tn++) {
                const int col  = jn + wn + tn * 16 + fm;
                const int row0 = im + mh * 64 + wm + tm * 16 + quad * 4;
                const float bv = HASBIAS ? bias[col] : 0.f;
#pragma unroll
                for (int r = 0; r < 4; r++)
                    Cb[(size_t)(row0 + r) * ldc + col] =
                        (_Float16)(acc[mh][tm][tn][r] + bv);
            }
}

// ---------------------------------------------------------------------------
// BM=128 x BN=128 DIRECT-DMA GEMM: 4 waves (2x2), each computing a 64x64
// sub-tile as 4x4 of 16x16 MFMA. Per wave K-step: 32 MFMA : 16 ds_read_b128
// : 8 DMA -- 2x hgemm2's MFMA density, half the barriers per FLOP. Same
// fragment layout (identical per-tile FP ordering -> absmax unchanged).
// Requires M % 128 == 0 and N % 128 == 0. LDS 32KB, acc 64 VGPR/lane.
// ---------------------------------------------------------------------------
template <bool SPLITA, bool HASBIAS>
__global__ __launch_bounds__(256, 2) void hgemm3_k(
    const _Float16* __restrict__ A, const _Float16* __restrict__ A2,
    const _Float16* __restrict__ B, const float* __restrict__ bias,
    _Float16* __restrict__ C, int M, int N, int K,
    int lda, int ldb, int ldc, long sA, long sB, int bdiv, long sC)
{
    const int jn = blockIdx.x * 128;
    const int im = blockIdx.y * 128;
    const int z  = blockIdx.z;
    const _Float16* Bb = B + (size_t)(z / bdiv) * sB;
    _Float16* Cb = C + (size_t)z * sC;

    __shared__ __align__(16) _Float16 As[128 * 64];
    __shared__ __align__(16) _Float16 Bs[128 * 64];

    const int tid  = threadIdx.x;
    const int lane = tid & 63;
    const int wv   = tid >> 6;
    const int wr   = (wv & 1) * 64;   // wave row base
    const int wc   = (wv >> 1) * 64;  // wave col base
    const int fm   = lane & 15;
    const int quad = lane >> 4;

    f32x4 acc[4][4];
#pragma unroll
    for (int m = 0; m < 4; m++)
#pragma unroll
        for (int n = 0; n < 4; n++) acc[m][n] = (f32x4)0.f;

    for (int k0 = 0; k0 < K; k0 += 64) {
        const int r8 = lane >> 3;
        const int kg = k0 + (lane & 7) * 8;
#pragma unroll
        for (int hh = 0; hh < 4; hh++) {
            const int rb = 8 * (wv + 4 * hh);   // 0..120: covers 128 rows
            const _Float16* gA;
            if constexpr (SPLITA) {
                const _Float16* Ah  = A  + (size_t)z * sA;
                const _Float16* A2h = A2 + (size_t)z * sA;
                gA = (kg < 256)
                    ? (Ah  + (size_t)(im + rb + r8) * lda + kg)
                    : (A2h + (size_t)(im + rb + r8) * lda + (kg - 256));
            } else {
                gA = A + (size_t)z * sA + (size_t)(im + rb + r8) * lda + kg;
            }
            gload16(gA, &As[rb * 64]);
            gload16(Bb + (size_t)(jn + rb + r8) * ldb + kg, &Bs[rb * 64]);
        }
        __syncthreads();

#pragma unroll
        for (int kh = 0; kh < 64; kh += 32) {
            half8 af[4], bf[4];
#pragma unroll
            for (int m = 0; m < 4; m++)
                af[m] = *(const half8*)(As + (wr + m * 16 + fm) * 64 + quad * 8 + kh);
#pragma unroll
            for (int n = 0; n < 4; n++)
                bf[n] = *(const half8*)(Bs + (wc + n * 16 + fm) * 64 + quad * 8 + kh);
#pragma unroll
            for (int m = 0; m < 4; m++)
#pragma unroll
                for (int n = 0; n < 4; n++)
                    acc[m][n] = __builtin_amdgcn_mfma_f32_16x16x32_f16(
                        af[m], bf[n], acc[m][n], 0, 0, 0);
        }
        __syncthreads();
    }

#pragma unroll
    for (int m = 0; m < 4; m++)
#pragma unroll
        for (int n = 0; n < 4; n++) {
            const int col  = jn + wc + n * 16 + fm;
            const int row0 = im + wr + m * 16 + quad * 4;
            const float bv = HASBIAS ? bias[col] : 0.f;
#pragma unroll
            for (int r = 0; r < 4; r++)
                Cb[(size_t)(row0 + r) * ldc + col] =
                    (_Float16)(acc[m][n][r] + bv);
        }
}

// ---------------------------------------------------------------------------
// GRU recurrence v15 (verified: ctx 307us, absmax 4.88e-4). Step ~1440 cyc
// floored by cross-wave LDS write->barrier->read turnaround + transcendental
// chain -- accepted as structural for this decomposition.
// ---------------------------------------------------------------------------
template <int TCMAX>
__global__ __launch_bounds__(512, 2) void gru_rec_k(
    const _Float16* __restrict__ gx,
    const _Float16* __restrict__ whh16,   // [2][384][128] fp16, dir-major
    const float* __restrict__ bhh_f, const float* __restrict__ bhh_b,
    _Float16* __restrict__ outs_h, float* __restrict__ hfin, int L)
{
    const int dir = blockIdx.x & 1;
    const int s   = blockIdx.x >> 1;
    const int t   = threadIdx.x;
    const int w   = t >> 6;
    const int l   = t & 63;
    const int i   = w * 16 + (l >> 2);  // output index (one per quad)
    const int kq  = l & 3;              // k-quarter within quad
    const _Float16* Wd = whh16 + (size_t)dir * 49152;
    const float* bh = dir ? bhh_b : bhh_f;

    h2_t w2[3][16];
#pragma unroll
    for (int j = 0; j < 3; j++) {
        const _Float16* Wr = Wd + (size_t)(i + 128 * j) * 128 + 32 * kq;
#pragma unroll
        for (int q = 0; q < 16; q++)
            w2[j][q] = *(const h2_t*)(Wr + 2 * q);
    }
    const float b0 = bh[i], b1 = bh[i + 128], b2 = bh[i + 256];

    __shared__ __align__(16) _Float16 h1[2][128];
    __shared__ __align__(16) _Float16 gxs[TCMAX][384];
    __shared__ __align__(16) _Float16 outb[TCMAX][128];
    if (t < 128) h1[0][t] = (_Float16)0.f;
    float hprev = 0.f;

    constexpr int NST = (TCMAX * 48 + 511) / 512;   // staging chunks/thread
    constexpr int NFL = (TCMAX * 16 + 511) / 512;   // flush chunks/thread

    for (int t0 = 0; t0 < L; t0 += TCMAX) {
        const int Tc = (L - t0 < TCMAX) ? (L - t0) : TCMAX;
        // stage gx tile (Tc*48 half8 chunks over 512 threads)
#pragma unroll
        for (int r = 0; r < NST; r++) {
            const int q = t + 512 * r;
            if (q < Tc * 48) {
                const int j = q / 48, off = (q % 48) * 8;
                const int tt = dir ? (L - 1 - (t0 + j)) : (t0 + j);
                *(half8*)&gxs[j][off] =
                    *(const half8*)(gx + ((size_t)s * L + tt) * 768 + dir * 384 + off);
            }
        }
        __syncthreads();   // drains staging; orders h1 init / prev flush

        for (int j = 0; j < Tc; j++) {
            const int cb = (t0 + j) & 1;
            const h2_t* hp = (const h2_t*)&h1[cb][32 * kq];
            float a0 = 0.f, a1 = 0.f, a2 = 0.f;
#pragma unroll
            for (int q = 0; q < 16; q++) {
                h2_t hq = hp[q];
                a0 = __builtin_amdgcn_fdot2(w2[0][q], hq, a0, false);
                a1 = __builtin_amdgcn_fdot2(w2[1][q], hq, a1, false);
                a2 = __builtin_amdgcn_fdot2(w2[2][q], hq, a2, false);
            }
            a0 = qsum4(a0);
            a1 = qsum4(a1);
            a2 = qsum4(a2);
            const float xc0 = (float)gxs[j][i];
            const float xc1 = (float)gxs[j][i + 128];
            const float xc2 = (float)gxs[j][i + 256];
            const float r  = fsig(xc0 + a0 + b0);
            const float zz = fsig(xc1 + a1 + b1);
            const float n  = ftanh(xc2 + r * (a2 + b2));
            const float hnew = (1.0f - zz) * n + zz * hprev;
            hprev = hnew;
            if (kq == 0) {
                h1[cb ^ 1][i] = (_Float16)hnew;
                outb[j][i]    = (_Float16)hnew;
            }
            __syncthreads();
        }

        // bulk flush outs tile (Tc*16 half8 chunks)
        if (outs_h) {
#pragma unroll
            for (int r = 0; r < NFL; r++) {
                const int q = t + 512 * r;
                if (q < Tc * 16) {
                    const int j = q / 16, off = (q % 16) * 8;
                    const int tt = dir ? (L - 1 - (t0 + j)) : (t0 + j);
                    *(half8*)(outs_h + ((size_t)s * L + tt) * 256 + dir * 128 + off) =
                        *(const half8*)&outb[j][off];
                }
            }
        }
    }
    if (hfin && kq == 0) hfin[(size_t)s * 256 + dir * 128 + i] = hprev;
}

// ---------------------------------------------------------------------------
// Row inverse norms over fp16 rows of 256: one 64-lane wave per row.
// ---------------------------------------------------------------------------
__global__ __launch_bounds__(64) void rowinv_k(const _Float16* __restrict__ x,
                                               float* __restrict__ rinv)
{
    const int row = blockIdx.x;
    const _Float16* p = x + (size_t)row * 256 + threadIdx.x * 4;
    const h2_t v0 = *(const h2_t*)p;
    const h2_t v1 = *(const h2_t*)(p + 2);
    float ss = (float)v0[0] * (float)v0[0] + (float)v0[1] * (float)v0[1]
             + (float)v1[0] * (float)v1[0] + (float)v1[1] * (float)v1[1];
#pragma unroll
    for (int o = 32; o > 0; o >>= 1) ss += __shfl_down(ss, o);
    if (threadIdx.x == 0)
        rinv[row] = 1.0f / fmaxf(sqrtf(ss), EPS);
}

// ---------------------------------------------------------------------------
// Fused cosine-scale + softmax (fp16 in/out, 512 positions).
// ---------------------------------------------------------------------------
__global__ __launch_bounds__(256) void att_softmax_k(
    _Float16* __restrict__ att, const float* __restrict__ rinv_opt_l,
    const float* __restrict__ rinv_ctx, int sbase)
{
    const int row = blockIdx.x;
    const int b = (sbase + row / 50) / 10;
    _Float16* p = att + (size_t)row * 512;
    const float* rc = rinv_ctx + b * 512;
    const float sA = rinv_opt_l[row];
    const int t = threadIdx.x;

    float v0 = (float)p[t]       * (sA * rc[t]);
    float v1 = (float)p[t + 256] * (sA * rc[t + 256]);

    __shared__ float red[4];
    float m = fmaxf(v0, v1);
#pragma unroll
    for (int o = 32; o > 0; o >>= 1) m = fmaxf(m, __shfl_down(m, o));
    if ((t & 63) == 0) red[t >> 6] = m;
    __syncthreads();
    m = fmaxf(fmaxf(red[0], red[1]), fmaxf(red[2], red[3]));
    float e0 = __expf(v0 - m), e1 = __expf(v1 - m);
    float ssum = e0 + e1;
#pragma unroll
    for (int o = 32; o > 0; o >>= 1) ssum += __shfl_down(ssum, o);
    __syncthreads();
    if ((t & 63) == 0) red[t >> 6] = ssum;
    __syncthreads();
    float inv = 1.0f / (red[0] + red[1] + red[2] + red[3]);
    p[t]       = (_Float16)(e0 * inv);
    p[t + 256] = (_Float16)(e1 * inv);
}

// ---------------------------------------------------------------------------
// logits[s] = cosine(ctx_h[s/10], ao_h[s])
// ---------------------------------------------------------------------------
__global__ __launch_bounds__(256) void logits_k(const float* __restrict__ ch,
                                                const float* __restrict__ ah,
                                                float* __restrict__ logits)
{
    const int s = blockIdx.x;
    const int b = s / 10;
    const int t = threadIdx.x;
    float a = ch[b * 256 + t];
    float c = ah[(size_t)s * 256 + t];
    float num = a * c, na = a * a, nc = c * c;
#pragma unroll
    for (int o = 32; o > 0; o >>= 1) {
        num += __shfl_down(num, o);
        na  += __shfl_down(na,  o);
        nc  += __shfl_down(nc,  o);
    }
    __shared__ float pn[4], pa[4], pc[4];
    if ((t & 63) == 0) { pn[t >> 6] = num; pa[t >> 6] = na; pc[t >> 6] = nc; }
    __syncthreads();
    if (t == 0) {
        float sn = pn[0] + pn[1] + pn[2] + pn[3];
        float sa = pa[0] + pa[1] + pa[2] + pa[3];
        float sc = pc[0] + pc[1] + pc[2] + pc[3];
        logits[s] = sn / (fmaxf(sqrtf(sa), EPS) * fmaxf(sqrtf(sc), EPS));
    }
}

// ---------------------------------------------------------------------------
__global__ __launch_bounds__(64) void soft10_k(const float* __restrict__ logits,
                                               float* __restrict__ out)
{
    const int b = blockIdx.x;
    const int t = threadIdx.x;
    __shared__ float v[10];
    if (t < 10) v[t] = logits[b * 10 + t];
    __syncthreads();
    if (t < 10) {
        float m = v[0];
#pragma unroll
        for (int i = 1; i < 10; i++) m = fmaxf(m, v[i]);
        float ssum = 0.f;
#pragma unroll
        for (int i = 0; i < 10; i++) ssum += __expf(v[i] - m);
        out[b * 10 + t] = __expf(v[t] - m) / ssum;
    }
}

// ---------------------------------------------------------------------------
extern "C" void kernel_launch(void* const* d_in, const int* in_sizes, int n_in,
                              void* d_out, int out_size, void* d_ws, size_t ws_size,
                              hipStream_t stream)
{
    const float* context = (const float*)d_in[0];
    const float* options = (const float*)d_in[2];
    const float* rw_ih_f = (const float*)d_in[4];
    const float* rw_hh_f = (const float*)d_in[5];
    const float* rb_ih_f = (const float*)d_in[6];
    const float* rb_hh_f = (const float*)d_in[7];
    const float* rw_ih_b = (const float*)d_in[8];
    const float* rw_hh_b = (const float*)d_in[9];
    const float* rb_ih_b = (const float*)d_in[10];
    const float* rb_hh_b = (const float*)d_in[11];
    const float* aw_ih_f = (const float*)d_in[12];
    const float* aw_hh_f = (const float*)d_in[13];
    const float* ab_ih_f = (const float*)d_in[14];
    const float* ab_hh_f = (const float*)d_in[15];
    const float* aw_ih_b = (const float*)d_in[16];
    const float* aw_hh_b = (const float*)d_in[17];
    const float* ab_ih_b = (const float*)d_in[18];
    const float* ab_hh_b = (const float*)d_in[19];

    // --- chunk config. persist(fl) = 15,222,144 (~60.9 MB).
    const size_t persist = 15222144;
    static const int cands[6][2] = {{1,2},{1,4},{2,4},{2,8},{4,16},{8,16}};
    int CC = 8, OC = 16;
    for (int idx = 0; idx < 6; idx++) {
        size_t bc_ = 64 / cands[idx][0], sc_ = 640 / cands[idx][1];
        size_t p = bc_ * 196608;
        if (sc_ * 32000 > p) p = sc_ * 32000;
        if ((persist + p + 2 * sc_ * 6400) * 4 <= ws_size) {
            CC = cands[idx][0]; OC = cands[idx][1]; break;
        }
    }
    const int bc = 64 / CC;
    const int sc = 640 / OC;
    size_t poolsz = (size_t)bc * 196608;
    if ((size_t)sc * 32000 > poolsz) poolsz = (size_t)sc * 32000;

    float* ws = (float*)d_ws;
    size_t off = 0;
    _Float16* wrh   = (_Float16*)(ws + off); off += 122880;   // [768][320] h
    float*    br    = ws + off;              off += 768;
    _Float16* wah   = (_Float16*)(ws + off); off += 196608;   // [768][512] h
    float*    ba    = ws + off;              off += 768;
    _Float16* wr16  = (_Float16*)(ws + off); off += 49152;    // [2][384][128] h
    _Float16* wa16  = (_Float16*)(ws + off); off += 49152;    // [2][384][128] h
    _Float16* couts = (_Float16*)(ws + off); off += 4194304;  // [64*512][256] h
    float*    ctxhf = ws + off;              off += 16384;    // ctx h_fin
    float*    aohf  = ws + off;              off += 163840;   // ao h_fin
    float*    logits= ws + off;              off += 640;
    float*    rinvc = ws + off;              off += 32768;
    float*    rinvo = ws + off;              off += 32000;
    _Float16* ctxh  = (_Float16*)(ws + off); off += 5242880;  // [32768][320] h
    _Float16* opth  = (_Float16*)(ws + off); off += 5120000;  // [32000][320] h
    _Float16* POOL  = (_Float16*)(ws + off); off += poolsz;   // gx pool (+ATT)
    _Float16* P2H   = (_Float16*)(ws + off); off += (size_t)sc * 6400;
    _Float16* P3H   = (_Float16*)(ws + off); off += (size_t)sc * 6400;
    _Float16* ATT   = POOL + (size_t)sc * 38400;  // halfs offset (= sc*19200 fl)

    // 1. weights -> fp16; inputs -> fp16 (padded K=320)
    prep_w_k<<<1536, 256, 0, stream>>>(rw_ih_f, rw_ih_b, aw_ih_f, aw_ih_b,
                                       rb_ih_f, rb_ih_b, ab_ih_f, ab_ih_b,
                                       rw_hh_f, rw_hh_b, aw_hh_f, aw_hh_b,
                                       wrh, wah, wr16, wa16, br, ba);
    conv_k<<<4096, 256, 0, stream>>>(context, options, ctxh, opth);

    // 2. context: gx GEMM (MFMA, 128x128-tile DIRECT DMA) + GRU per chunk
    for (int c = 0; c < CC; c++) {
        const int Mc = bc * 512;   // always % 128 == 0; N=768 % 128 == 0
        hgemm3_k<false, true><<<dim3(6, Mc / 128, 1), 256, 0, stream>>>(
            ctxh + (size_t)c * Mc * 320, nullptr, wrh, br, POOL,
            Mc, 768, 320, 320, 320, 768, 0, 0, 1, 0);
        gru_rec_k<64><<<2 * bc, 512, 0, stream>>>(
            POOL, wr16, rb_hh_f, rb_hh_b,
            couts + (size_t)c * Mc * 256, ctxhf + (size_t)c * bc * 256, 512);
    }

    // 3. ctx row inverse norms (1 wave per row)
    rowinv_k<<<32768, 64, 0, stream>>>(couts, rinvc);

    // 4. options: per chunk pipeline
    for (int o = 0; o < OC; o++) {
        const int base = o * sc;
        const int Mo = sc * 50;
        const _Float16* ctxB = couts + (size_t)(base / 10) * 131072;

        // 4a. opt gx (MFMA) -> POOL[0 .. sc*38400 halfs)
        if ((Mo % 128) == 0)
            hgemm3_k<false, true><<<dim3(6, Mo / 128, 1), 256, 0, stream>>>(
                opth + (size_t)base * 50 * 320, nullptr, wrh, br, POOL,
                Mo, 768, 320, 320, 320, 768, 0, 0, 1, 0);
        else if ((Mo % 64) == 0)
            hgemm_k<false, false, true, true><<<dim3(12, Mo / 64, 1), 256, 0, stream>>>(
                opth + (size_t)base * 50 * 320, nullptr, wrh, br, POOL,
                Mo, 768, 320, 320, 320, 768, 0, 0, 1, 0);
        else
            hgemm_k<false, false, true, false><<<dim3(12, (Mo + 63) / 64, 1), 256, 0, stream>>>(
                opth + (size_t)base * 50 * 320, nullptr, wrh, br, POOL,
                Mo, 768, 320, 320, 320, 768, 0, 0, 1, 0);
        // 4b. opt GRU -> P2H   (opt gx dead after this)
        gru_rec_k<50><<<2 * sc, 512, 0, stream>>>(
            POOL, wr16, rb_hh_f, rb_hh_b, P2H, nullptr, 50);
        // 4c. opt row inverse norms (1 wave per row)
        rowinv_k<<<Mo, 64, 0, stream>>>(P2H, rinvo + (size_t)base * 50);
        // 4d. raw scores (MFMA, NT, batched): ATT = P2H @ ctxB^T
        hgemm_k<false, false, false, false><<<dim3(8, 1, sc), 256, 0, stream>>>(
            P2H, nullptr, ctxB, nullptr, ATT,
            50, 512, 256, 256, 256, 512, 12800, 131072, 10, 25600);
        // 4e. fused cosine scaling + softmax (fp16 in-place)
        att_softmax_k<<<Mo, 256, 0, stream>>>(ATT, rinvo + (size_t)base * 50,
                                              rinvc, base);
        // 4f. att_opt (MFMA, NN via transpose-stage): P3H = ATT @ ctxB
        hgemm_k<true, false, false, false><<<dim3(4, 1, sc), 256, 0, stream>>>(
            ATT, nullptr, ctxB, nullptr, P3H,
            50, 256, 512, 512, 256, 256, 25600, 131072, 10, 12800);
        // 4g. attn gx (MFMA, split-A K=512) -> POOL[0 ..) (opt-gx region, dead)
        if ((Mo % 128) == 0)
            hgemm3_k<true, true><<<dim3(6, Mo / 128, 1), 256, 0, stream>>>(
                P3H, P2H, wah, ba, POOL,
                Mo, 768, 512, 256, 512, 768, 0, 0, 1, 0);
        else if ((Mo % 64) == 0)
            hgemm_k<false, true, true, true><<<dim3(12, Mo / 64, 1), 256, 0, stream>>>(
                P3H, P2H, wah, ba, POOL,
                Mo, 768, 512, 256, 512, 768, 0, 0, 1, 0);
        else
            hgemm_k<false, true, true, false><<<dim3(12, (Mo + 63) / 64, 1), 256, 0, stream>>>(
                P3H, P2H, wah, ba, POOL,
                Mo, 768, 512, 256, 512, 768, 0, 0, 1, 0);
        // 4h. attn GRU -> ao_h
        gru_rec_k<50><<<2 * sc, 512, 0, stream>>>(
            POOL, wa16, ab_hh_f, ab_hh_b, nullptr, aohf + (size_t)base * 256, 50);
    }

    // 5. cosine logits + final softmax
    logits_k<<<640, 256, 0, stream>>>(ctxhf, aohf, logits);
    soft10_k<<<64, 64, 0, stream>>>(logits, (float*)d_out);
}